// Round 10
// baseline (686.129 us; speedup 1.0000x reference)
//
#include <hip/hip_runtime.h>
#include <hip/hip_fp16.h>

#define N_NODES 100000
#define N_EDGES 1600000
#define NB 64
#define F_INn 64
#define HID 16
#define NL 4
#define NSCAN_BLK 391   // ceil(N_NODES/256) (fallback path)
#define NBIN 512
#define BINW 196        // ceil(100000/512); 196*512 = 100352 >= N
#define NPBLK 512

__device__ __forceinline__ unsigned pack2h(float a, float b) {
    __half2 h = __floats2half2_rn(a, b);
    return *reinterpret_cast<unsigned*>(&h);
}

__device__ __forceinline__ void blk_range(int blk, int& e0, int& e1) {
    e0 = (int)(((long long)blk * N_EDGES) / NPBLK);
    e1 = (int)(((long long)(blk + 1) * N_EDGES) / NPBLK);
}

// ---------------- node embedding: y0 = x @ node_w + node_b ----------------
__global__ __launch_bounds__(256) void k_embed(
    const float* __restrict__ x, const float* __restrict__ nw,
    const float* __restrict__ nb, float* __restrict__ yout)
{
    __shared__ float xs[16 * 64];
    __shared__ float Wn[64 * 16];
    __shared__ float Bn[16];
    const int tid = threadIdx.x;
    for (int i = tid; i < 1024; i += 256) Wn[i] = nw[i];
    if (tid < 16) Bn[tid] = nb[tid];
    const int n0 = blockIdx.x * 16;
    reinterpret_cast<float4*>(xs)[tid] =
        reinterpret_cast<const float4*>(x + (size_t)n0 * F_INn)[tid];
    __syncthreads();
    const int nl = tid >> 4, j = tid & 15;
    float acc = Bn[j];
    #pragma unroll 8
    for (int k = 0; k < 64; ++k) acc += xs[nl * 64 + k] * Wn[k * 16 + j];
    yout[(size_t)(n0 + nl) * HID + j] = acc;
}

// ================= binned CSR build (no random global atomics) ============
__global__ __launch_bounds__(256) void k_hist1(
    const int* __restrict__ dstA, int* __restrict__ histG)
{
    __shared__ int h[NBIN];
    const int tid = threadIdx.x, blk = blockIdx.x;
    for (int t = tid; t < NBIN; t += 256) h[t] = 0;
    __syncthreads();
    int e0, e1; blk_range(blk, e0, e1);
    for (int e = e0 + tid; e < e1; e += 256)
        atomicAdd(&h[dstA[e] / BINW], 1);
    __syncthreads();
    for (int t = tid; t < NBIN; t += 256) histG[blk * NBIN + t] = h[t];
}

__global__ __launch_bounds__(NPBLK) void k_scanblk(
    const int* __restrict__ histG, int* __restrict__ boffsG,
    int* __restrict__ binTot)
{
    __shared__ int sc[NPBLK];
    const int tid = threadIdx.x, bin = blockIdx.x;
    const int v = histG[tid * NBIN + bin];
    sc[tid] = v;
    __syncthreads();
    for (int off = 1; off < NPBLK; off <<= 1) {
        int t = (tid >= off) ? sc[tid - off] : 0;
        __syncthreads();
        sc[tid] += t;
        __syncthreads();
    }
    boffsG[tid * NBIN + bin] = sc[tid] - v;
    if (tid == NPBLK - 1) binTot[bin] = sc[tid];
}

__global__ __launch_bounds__(NBIN) void k_scanbin(
    const int* __restrict__ binTot, int* __restrict__ binStart)
{
    __shared__ int sc[NBIN];
    const int tid = threadIdx.x;
    const int v = binTot[tid];
    sc[tid] = v;
    __syncthreads();
    for (int off = 1; off < NBIN; off <<= 1) {
        int t = (tid >= off) ? sc[tid - off] : 0;
        __syncthreads();
        sc[tid] += t;
        __syncthreads();
    }
    binStart[tid] = sc[tid] - v;
    if (tid == NBIN - 1) binStart[NBIN] = sc[tid];
}

// partition + edge-MLP; 1 lane/edge (coalesced eattr), streamed a-loads
__global__ __launch_bounds__(256, 6) void k_part2(
    const int* __restrict__ dstA, const int* __restrict__ srcA,
    const float* __restrict__ eattr, const float* __restrict__ ew,
    const float* __restrict__ ebv, const int* __restrict__ boffsG,
    const int* __restrict__ binStart, int* __restrict__ partDS,
    __half* __restrict__ partE)
{
    __shared__ float EW[256];
    __shared__ float EB[16];
    __shared__ int cur[NBIN];
    const int tid = threadIdx.x, blk = blockIdx.x;
    EW[tid] = ew[tid];
    if (tid < 16) EB[tid] = ebv[tid];
    for (int t = tid; t < NBIN; t += 256)
        cur[t] = binStart[t] + boffsG[blk * NBIN + t];
    __syncthreads();
    int e0, e1; blk_range(blk, e0, e1);
    for (int e = e0 + tid; e < e1; e += 256) {
        const int d = dstA[e];
        const int bin = d / BINW;
        const int dloc = d - bin * BINW;
        float acc[16];
        #pragma unroll
        for (int j = 0; j < 16; ++j) acc[j] = EB[j];
        const float4* ag = reinterpret_cast<const float4*>(eattr + ((size_t)e << 4));
        #pragma unroll
        for (int q = 0; q < 4; ++q) {
            const float4 av = ag[q];
            #pragma unroll
            for (int j = 0; j < 16; ++j) {
                acc[j] += av.x * EW[(q * 4 + 0) * 16 + j];
                acc[j] += av.y * EW[(q * 4 + 1) * 16 + j];
                acc[j] += av.z * EW[(q * 4 + 2) * 16 + j];
                acc[j] += av.w * EW[(q * 4 + 3) * 16 + j];
            }
        }
        const int p = atomicAdd(&cur[bin], 1);
        partDS[p] = (dloc << 17) | srcA[e];
        uint4 lo, hi;
        lo.x = pack2h(acc[0], acc[1]);   lo.y = pack2h(acc[2], acc[3]);
        lo.z = pack2h(acc[4], acc[5]);   lo.w = pack2h(acc[6], acc[7]);
        hi.x = pack2h(acc[8], acc[9]);   hi.y = pack2h(acc[10], acc[11]);
        hi.z = pack2h(acc[12], acc[13]); hi.w = pack2h(acc[14], acc[15]);
        uint4* eo = reinterpret_cast<uint4*>(partE) + ((size_t)p << 1);
        eo[0] = lo;
        eo[1] = hi;
    }
}

// fused per-bin: count + scan -> rowptr, then place payload at CSR position
__global__ __launch_bounds__(512) void k_finish(
    const int* __restrict__ partDS, const __half* __restrict__ partE,
    const int* __restrict__ binStart, int* __restrict__ rowptr,
    int* __restrict__ srcP, __half* __restrict__ eaPh)
{
    __shared__ int h[BINW];
    __shared__ int sc[512];
    __shared__ int cur[BINW];
    const int tid = threadIdx.x, bin = blockIdx.x;
    const int base = bin * BINW;
    for (int t = tid; t < BINW; t += 512) h[t] = 0;
    __syncthreads();
    const int i0 = binStart[bin], i1 = binStart[bin + 1];
    for (int i = i0 + tid; i < i1; i += 512)
        atomicAdd(&h[partDS[i] >> 17], 1);
    __syncthreads();
    const int v = (tid < BINW) ? h[tid] : 0;
    sc[tid] = v;
    __syncthreads();
    for (int off = 1; off < 512; off <<= 1) {
        int t = (tid >= off) ? sc[tid - off] : 0;
        __syncthreads();
        sc[tid] += t;
        __syncthreads();
    }
    if (tid < BINW) {
        const int r = i0 + sc[tid] - v;
        const int idx = base + tid;
        if (idx < N_NODES) rowptr[idx] = r;
        cur[tid] = r;
    }
    if (bin == NBIN - 1 && tid == 0) rowptr[N_NODES] = N_EDGES;
    __syncthreads();
    for (int i = i0 + tid; i < i1; i += 512) {
        const int w = partDS[i];
        const int dloc = w >> 17;
        const int p = atomicAdd(&cur[dloc], 1);
        srcP[p] = w & 131071;
        const uint4* si = reinterpret_cast<const uint4*>(partE) + ((size_t)i << 1);
        uint4* di = reinterpret_cast<uint4*>(eaPh) + ((size_t)p << 1);
        di[0] = si[0];
        di[1] = si[1];
    }
}

// ---------------- v0 fallback CSR build pieces ----------------
__global__ __launch_bounds__(256) void k_count(
    const int* __restrict__ dstA, int* __restrict__ cnt)
{
    const int e = blockIdx.x * 256 + threadIdx.x;
    if (e < N_EDGES) atomicAdd(cnt + dstA[e], 1);
}

__global__ __launch_bounds__(256) void k_scan1(
    const int* __restrict__ cnt, int* __restrict__ rowptr, int* __restrict__ bsum)
{
    __shared__ int sc[256];
    const int tid = threadIdx.x;
    const int i = blockIdx.x * 256 + tid;
    const int v = (i < N_NODES) ? cnt[i] : 0;
    sc[tid] = v;
    __syncthreads();
    for (int off = 1; off < 256; off <<= 1) {
        int t = (tid >= off) ? sc[tid - off] : 0;
        __syncthreads();
        sc[tid] += t;
        __syncthreads();
    }
    if (i < N_NODES) rowptr[i] = sc[tid] - v;
    if (tid == 255) bsum[blockIdx.x] = sc[tid];
}

__global__ __launch_bounds__(512) void k_scan2(
    const int* __restrict__ bsum, int* __restrict__ offs, int* __restrict__ rowptr)
{
    __shared__ int sc[512];
    const int tid = threadIdx.x;
    const int v = (tid < NSCAN_BLK) ? bsum[tid] : 0;
    sc[tid] = v;
    __syncthreads();
    for (int off = 1; off < 512; off <<= 1) {
        int t = (tid >= off) ? sc[tid - off] : 0;
        __syncthreads();
        sc[tid] += t;
        __syncthreads();
    }
    if (tid < NSCAN_BLK) offs[tid] = sc[tid] - v;
    if (tid == NSCAN_BLK - 1) rowptr[N_NODES] = sc[tid];
}

__global__ __launch_bounds__(256) void k_scan3(
    int* __restrict__ rowptr, const int* __restrict__ offs, int* __restrict__ cnt)
{
    const int i = blockIdx.x * 256 + threadIdx.x;
    if (i < N_NODES) {
        rowptr[i] += offs[i >> 8];
        cnt[i] = 0;
    }
}

__global__ __launch_bounds__(256) void k_fill(
    const int* __restrict__ dstA, const int* __restrict__ rowptr,
    int* __restrict__ cnt, int* __restrict__ csr)
{
    const int e = blockIdx.x * 256 + threadIdx.x;
    if (e >= N_EDGES) return;
    const int d = dstA[e];
    const int pos = atomicAdd(cnt + d, 1);
    csr[rowptr[d] + pos] = e;
}

// ---------------- per-layer aggregation: 16 lanes/node, fp16 ea ----------
__global__ __launch_bounds__(256, 8) void k_aggr(
    const float* __restrict__ yin, const int* __restrict__ rowptr,
    const int* __restrict__ srcP, const __half* __restrict__ eaPh,
    const float* __restrict__ tArr, int layer, float* __restrict__ aggr)
{
    const int t = blockIdx.x * 256 + threadIdx.x;
    const int n = t >> 4;
    if (n >= N_NODES) return;
    const int sub = threadIdx.x & 15;
    const int es = sub >> 2, cg = sub & 3;
    const int row0 = rowptr[n], row1 = rowptr[n + 1];
    const float tv = tArr[layer];

    float4 s = make_float4(0.f, 0.f, 0.f, 0.f);
    float4 num = make_float4(0.f, 0.f, 0.f, 0.f);

    int i = row0 + es;
    bool has = (i < row1);
    int spn = 0;
    uint2 ean = make_uint2(0u, 0u);
    if (has) {
        spn = srcP[i];
        ean = reinterpret_cast<const uint2*>(eaPh + ((size_t)i << 4))[cg];
    }
    while (has) {
        const int sp = spn;
        const uint2 eaw = ean;
        const int i2 = i + 4;
        const bool has2 = (i2 < row1);
        if (has2) {
            spn = srcP[i2];
            ean = reinterpret_cast<const uint2*>(eaPh + ((size_t)i2 << 4))[cg];
        }
        const float4 yv = reinterpret_cast<const float4*>(yin + ((size_t)sp << 4))[cg];
        const float2 f0 = __half22float2(*reinterpret_cast<const __half2*>(&eaw.x));
        const float2 f1 = __half22float2(*reinterpret_cast<const __half2*>(&eaw.y));
        float m, ez;
        m = fmaxf(yv.x + f0.x, 0.f) + 1e-7f; ez = __expf(tv * m); s.x += ez; num.x += m * ez;
        m = fmaxf(yv.y + f0.y, 0.f) + 1e-7f; ez = __expf(tv * m); s.y += ez; num.y += m * ez;
        m = fmaxf(yv.z + f1.x, 0.f) + 1e-7f; ez = __expf(tv * m); s.z += ez; num.z += m * ez;
        m = fmaxf(yv.w + f1.y, 0.f) + 1e-7f; ez = __expf(tv * m); s.w += ez; num.w += m * ez;
        i = i2; has = has2;
    }
    s.x += __shfl_xor(s.x, 4); s.y += __shfl_xor(s.y, 4);
    s.z += __shfl_xor(s.z, 4); s.w += __shfl_xor(s.w, 4);
    num.x += __shfl_xor(num.x, 4); num.y += __shfl_xor(num.y, 4);
    num.z += __shfl_xor(num.z, 4); num.w += __shfl_xor(num.w, 4);
    s.x += __shfl_xor(s.x, 8); s.y += __shfl_xor(s.y, 8);
    s.z += __shfl_xor(s.z, 8); s.w += __shfl_xor(s.w, 8);
    num.x += __shfl_xor(num.x, 8); num.y += __shfl_xor(num.y, 8);
    num.z += __shfl_xor(num.z, 8); num.w += __shfl_xor(num.w, 8);
    if (es == 0) {
        float4 r;
        r.x = num.x / (s.x + 1e-16f);
        r.y = num.y / (s.y + 1e-16f);
        r.z = num.z / (s.z + 1e-16f);
        r.w = num.w / (s.w + 1e-16f);
        reinterpret_cast<float4*>(aggr + ((size_t)n << 4))[cg] = r;
    }
}

// ---------------- node pass: MLP + residual + next-norm ----------------
__global__ __launch_bounds__(256) void k_node(
    const float* __restrict__ yin, const float* __restrict__ hprev,
    const float* __restrict__ aggr,
    const float* __restrict__ w1, const float* __restrict__ b1,
    const float* __restrict__ g1, const float* __restrict__ be1,
    const float* __restrict__ w2, const float* __restrict__ b2,
    const float* __restrict__ gn, const float* __restrict__ bn,
    float* __restrict__ hout, float* __restrict__ yout, int layer)
{
    __shared__ float4 W1[128];
    __shared__ float4 W2[128];
    __shared__ float B1[32], G1[32], BE1[32], B2[16], GN[16], BN[16];
    const int tid = threadIdx.x;
    if (tid < 128) {
        W1[tid] = reinterpret_cast<const float4*>(w1)[tid];
        W2[tid] = reinterpret_cast<const float4*>(w2)[tid];
    }
    if (tid < 32) { B1[tid] = b1[tid]; G1[tid] = g1[tid]; BE1[tid] = be1[tid]; }
    if (tid < 16) { B2[tid] = b2[tid]; GN[tid] = gn[tid]; BN[tid] = bn[tid]; }
    __syncthreads();
    const int n = blockIdx.x * 256 + tid;
    if (n >= N_NODES) return;
    const size_t base = (size_t)n * HID;

    float hin[16];
    {
        const float4* yg = reinterpret_cast<const float4*>(yin + base);
        const float4* ag = reinterpret_cast<const float4*>(aggr + base);
        #pragma unroll
        for (int q = 0; q < 4; ++q) {
            float4 yv = yg[q], av = ag[q];
            hin[q * 4 + 0] = yv.x + av.x;
            hin[q * 4 + 1] = yv.y + av.y;
            hin[q * 4 + 2] = yv.z + av.z;
            hin[q * 4 + 3] = yv.w + av.w;
        }
    }
    float z[32];
    #pragma unroll
    for (int i = 0; i < 32; ++i) z[i] = B1[i];
    #pragma unroll
    for (int j = 0; j < 16; ++j) {
        const float hv = hin[j];
        #pragma unroll
        for (int q = 0; q < 8; ++q) {
            float4 w = W1[j * 8 + q];
            z[q * 4 + 0] += hv * w.x; z[q * 4 + 1] += hv * w.y;
            z[q * 4 + 2] += hv * w.z; z[q * 4 + 3] += hv * w.w;
        }
    }
    float mu = 0.f;
    #pragma unroll
    for (int i = 0; i < 32; ++i) mu += z[i];
    mu *= (1.f / 32.f);
    float var = 0.f;
    #pragma unroll
    for (int i = 0; i < 32; ++i) { float d = z[i] - mu; var += d * d; }
    var *= (1.f / 32.f);
    const float rs = rsqrtf(var + 1e-5f);

    float o[16];
    #pragma unroll
    for (int j = 0; j < 16; ++j) o[j] = B2[j];
    #pragma unroll
    for (int i = 0; i < 32; ++i) {
        const float r = fmaxf((z[i] - mu) * rs * G1[i] + BE1[i], 0.f);
        #pragma unroll
        for (int q = 0; q < 4; ++q) {
            float4 w = W2[i * 4 + q];
            o[q * 4 + 0] += r * w.x; o[q * 4 + 1] += r * w.y;
            o[q * 4 + 2] += r * w.z; o[q * 4 + 3] += r * w.w;
        }
    }
    float hn[16];
    if (layer == 0) {
        #pragma unroll
        for (int j = 0; j < 16; ++j) hn[j] = o[j];
    } else {
        const float4* hg = reinterpret_cast<const float4*>(hprev + base);
        float hr[16];
        *reinterpret_cast<float4*>(&hr[0])  = hg[0];
        *reinterpret_cast<float4*>(&hr[4])  = hg[1];
        *reinterpret_cast<float4*>(&hr[8])  = hg[2];
        *reinterpret_cast<float4*>(&hr[12]) = hg[3];
        #pragma unroll
        for (int j = 0; j < 16; ++j) hn[j] = hr[j] + o[j];
    }
    {
        float4* ho = reinterpret_cast<float4*>(hout + base);
        #pragma unroll
        for (int q = 0; q < 4; ++q)
            ho[q] = make_float4(hn[q*4+0], hn[q*4+1], hn[q*4+2], hn[q*4+3]);
    }
    float mu2 = 0.f;
    #pragma unroll
    for (int j = 0; j < 16; ++j) mu2 += hn[j];
    mu2 *= (1.f / 16.f);
    float v2 = 0.f;
    #pragma unroll
    for (int j = 0; j < 16; ++j) { float d = hn[j] - mu2; v2 += d * d; }
    v2 *= (1.f / 16.f);
    const float rs2 = rsqrtf(v2 + 1e-5f);
    float yn[16];
    #pragma unroll
    for (int j = 0; j < 16; ++j)
        yn[j] = fmaxf((hn[j] - mu2) * rs2 * GN[j] + BN[j], 0.f);
    {
        float4* yo = reinterpret_cast<float4*>(yout + base);
        #pragma unroll
        for (int q = 0; q < 4; ++q)
            yo[q] = make_float4(yn[q*4+0], yn[q*4+1], yn[q*4+2], yn[q*4+3]);
    }
}

// ---------------- v0 FALLBACK fused layer (round-4, proven) --------------
__global__ __launch_bounds__(256) void k_layer(
    const float* __restrict__ yin, const float* __restrict__ hprev,
    const int* __restrict__ rowptr, const int* __restrict__ csr,
    const int* __restrict__ srcA, const float* __restrict__ eattr,
    const float* __restrict__ ew, const float* __restrict__ ebv,
    const float* __restrict__ tArr, int layer,
    const float* __restrict__ w1, const float* __restrict__ b1,
    const float* __restrict__ g1, const float* __restrict__ be1,
    const float* __restrict__ w2, const float* __restrict__ b2,
    const float* __restrict__ gn, const float* __restrict__ bn,
    float* __restrict__ hout, float* __restrict__ yout)
{
    __shared__ float EW[256];
    __shared__ float EB[16];
    __shared__ float4 W1[128];
    __shared__ float4 W2[128];
    __shared__ float B1[32], G1[32], BE1[32], B2[16], GN[16], BN[16];
    const int tid = threadIdx.x;
    EW[tid] = ew[tid];
    if (tid < 128) {
        W1[tid] = reinterpret_cast<const float4*>(w1)[tid];
        W2[tid] = reinterpret_cast<const float4*>(w2)[tid];
    }
    if (tid < 32) { B1[tid] = b1[tid]; G1[tid] = g1[tid]; BE1[tid] = be1[tid]; }
    if (tid < 16) { EB[tid] = ebv[tid]; B2[tid] = b2[tid]; GN[tid] = gn[tid]; BN[tid] = bn[tid]; }
    __syncthreads();

    const int t = blockIdx.x * 256 + tid;
    const int n = t >> 2, sub = t & 3;
    if (n >= N_NODES) return;
    const int row0 = rowptr[n], row1 = rowptr[n + 1];
    const float tv = tArr[layer];

    float s[16], num[16];
    #pragma unroll
    for (int j = 0; j < 16; ++j) { s[j] = 0.f; num[j] = 0.f; }

    for (int i = row0 + sub; i < row1; i += 4) {
        const int eid = csr[i];
        const int sp = srcA[eid];
        float a[16], yv[16];
        {
            const float4* ag = reinterpret_cast<const float4*>(eattr + (size_t)eid * 16);
            *reinterpret_cast<float4*>(&a[0])  = ag[0];
            *reinterpret_cast<float4*>(&a[4])  = ag[1];
            *reinterpret_cast<float4*>(&a[8])  = ag[2];
            *reinterpret_cast<float4*>(&a[12]) = ag[3];
            const float4* yg = reinterpret_cast<const float4*>(yin + (size_t)sp * 16);
            *reinterpret_cast<float4*>(&yv[0])  = yg[0];
            *reinterpret_cast<float4*>(&yv[4])  = yg[1];
            *reinterpret_cast<float4*>(&yv[8])  = yg[2];
            *reinterpret_cast<float4*>(&yv[12]) = yg[3];
        }
        float acc[16];
        #pragma unroll
        for (int j = 0; j < 16; ++j) acc[j] = EB[j];
        #pragma unroll
        for (int k = 0; k < 16; ++k) {
            const float av = a[k];
            #pragma unroll
            for (int j = 0; j < 16; ++j) acc[j] += av * EW[k * 16 + j];
        }
        #pragma unroll
        for (int j = 0; j < 16; ++j) {
            float m = fmaxf(yv[j] + acc[j], 0.f) + 1e-7f;
            float ez = __expf(tv * m);
            s[j] += ez;
            num[j] += m * ez;
        }
    }
    #pragma unroll
    for (int j = 0; j < 16; ++j) {
        s[j]   += __shfl_xor(s[j], 1);   num[j] += __shfl_xor(num[j], 1);
        s[j]   += __shfl_xor(s[j], 2);   num[j] += __shfl_xor(num[j], 2);
    }
    if (sub != 0) return;

    const size_t base = (size_t)n * HID;
    float hin[16];
    {
        const float4* yg = reinterpret_cast<const float4*>(yin + base);
        float yr[16];
        *reinterpret_cast<float4*>(&yr[0])  = yg[0];
        *reinterpret_cast<float4*>(&yr[4])  = yg[1];
        *reinterpret_cast<float4*>(&yr[8])  = yg[2];
        *reinterpret_cast<float4*>(&yr[12]) = yg[3];
        #pragma unroll
        for (int j = 0; j < 16; ++j) hin[j] = yr[j] + num[j] / (s[j] + 1e-16f);
    }
    float z[32];
    #pragma unroll
    for (int i = 0; i < 32; ++i) z[i] = B1[i];
    #pragma unroll
    for (int j = 0; j < 16; ++j) {
        const float hv = hin[j];
        #pragma unroll
        for (int q = 0; q < 8; ++q) {
            float4 w = W1[j * 8 + q];
            z[q * 4 + 0] += hv * w.x; z[q * 4 + 1] += hv * w.y;
            z[q * 4 + 2] += hv * w.z; z[q * 4 + 3] += hv * w.w;
        }
    }
    float mu = 0.f;
    #pragma unroll
    for (int i = 0; i < 32; ++i) mu += z[i];
    mu *= (1.f / 32.f);
    float var = 0.f;
    #pragma unroll
    for (int i = 0; i < 32; ++i) { float d = z[i] - mu; var += d * d; }
    var *= (1.f / 32.f);
    const float rs = rsqrtf(var + 1e-5f);

    float o[16];
    #pragma unroll
    for (int j = 0; j < 16; ++j) o[j] = B2[j];
    #pragma unroll
    for (int i = 0; i < 32; ++i) {
        const float r = fmaxf((z[i] - mu) * rs * G1[i] + BE1[i], 0.f);
        #pragma unroll
        for (int q = 0; q < 4; ++q) {
            float4 w = W2[i * 4 + q];
            o[q * 4 + 0] += r * w.x; o[q * 4 + 1] += r * w.y;
            o[q * 4 + 2] += r * w.z; o[q * 4 + 3] += r * w.w;
        }
    }
    float hn[16];
    if (layer == 0) {
        #pragma unroll
        for (int j = 0; j < 16; ++j) hn[j] = o[j];
    } else {
        const float4* hg = reinterpret_cast<const float4*>(hprev + base);
        float hr[16];
        *reinterpret_cast<float4*>(&hr[0])  = hg[0];
        *reinterpret_cast<float4*>(&hr[4])  = hg[1];
        *reinterpret_cast<float4*>(&hr[8])  = hg[2];
        *reinterpret_cast<float4*>(&hr[12]) = hg[3];
        #pragma unroll
        for (int j = 0; j < 16; ++j) hn[j] = hr[j] + o[j];
    }
    {
        float4* ho = reinterpret_cast<float4*>(hout + base);
        #pragma unroll
        for (int q = 0; q < 4; ++q)
            ho[q] = make_float4(hn[q*4+0], hn[q*4+1], hn[q*4+2], hn[q*4+3]);
    }
    float mu2 = 0.f;
    #pragma unroll
    for (int j = 0; j < 16; ++j) mu2 += hn[j];
    mu2 *= (1.f / 16.f);
    float v2 = 0.f;
    #pragma unroll
    for (int j = 0; j < 16; ++j) { float d = hn[j] - mu2; v2 += d * d; }
    v2 *= (1.f / 16.f);
    const float rs2 = rsqrtf(v2 + 1e-5f);
    float yn[16];
    #pragma unroll
    for (int j = 0; j < 16; ++j)
        yn[j] = fmaxf((hn[j] - mu2) * rs2 * GN[j] + BN[j], 0.f);
    {
        float4* yo = reinterpret_cast<float4*>(yout + base);
        #pragma unroll
        for (int q = 0; q < 4; ++q)
            yo[q] = make_float4(yn[q*4+0], yn[q*4+1], yn[q*4+2], yn[q*4+3]);
    }
}

// ---------------- pooling: one block per graph, no atomics ----------------
__global__ __launch_bounds__(256) void k_pool(
    const float* __restrict__ y, const int* __restrict__ batch,
    float* __restrict__ gmax, float* __restrict__ gsum, float* __restrict__ gcnt)
{
    const int g = blockIdx.x;
    const int tid = threadIdx.x;
    int lo = 0, hi = N_NODES;
    while (lo < hi) { int mid = (lo + hi) >> 1; if (batch[mid] < g) lo = mid + 1; else hi = mid; }
    const int start = lo;
    lo = 0; hi = N_NODES;
    while (lo < hi) { int mid = (lo + hi) >> 1; if (batch[mid] < g + 1) lo = mid + 1; else hi = mid; }
    const int end = lo;

    const int ch = tid & 15, slot = tid >> 4;
    float mx = 0.f, sm = 0.f;
    for (int n = start + slot; n < end; n += 16) {
        float v = y[(size_t)n * HID + ch];
        mx = fmaxf(mx, v);
        sm += v;
    }
    __shared__ float rm[256], rsum[256];
    rm[tid] = mx; rsum[tid] = sm;
    __syncthreads();
    for (int off = 8; off >= 1; off >>= 1) {
        if (slot < off) {
            rm[tid] = fmaxf(rm[tid], rm[tid + off * 16]);
            rsum[tid] += rsum[tid + off * 16];
        }
        __syncthreads();
    }
    if (slot == 0) {
        gmax[g * HID + ch] = rm[ch];
        gsum[g * HID + ch] = rsum[ch];
        if (ch == 0) gcnt[g] = (float)(end - start);
    }
}

// ---------------- final MLP head ----------------
__global__ __launch_bounds__(128) void k_final(
    const float* __restrict__ gmax, const float* __restrict__ gsum,
    const float* __restrict__ gcnt, const float* __restrict__ action,
    const float* __restrict__ pin_w, const float* __restrict__ pin_b,
    const float* __restrict__ ph_w, const float* __restrict__ ph_b,
    const float* __restrict__ po_w, const float* __restrict__ po_b,
    float* __restrict__ out)
{
    __shared__ float mol[32];
    __shared__ float fpv[128];
    __shared__ float pol[10];
    const int b = blockIdx.x, tid = threadIdx.x;
    if (tid < 16) mol[tid] = gmax[b * 16 + tid];
    else if (tid < 32) mol[tid] = gsum[b * 16 + (tid - 16)] / gcnt[b];
    __syncthreads();
    float acc = pin_b[tid];
    #pragma unroll 4
    for (int k = 0; k < 32; ++k) acc += mol[k] * pin_w[k * 128 + tid];
    fpv[tid] = fmaxf(acc, 0.f);
    __syncthreads();
    if (tid < 10) {
        float a2 = ph_b[tid];
        for (int k = 0; k < 128; ++k) a2 += fpv[k] * ph_w[k * 10 + tid];
        #pragma unroll
        for (int k = 0; k < 6; ++k) a2 += action[b * 6 + k] * ph_w[(128 + k) * 10 + tid];
        pol[tid] = fmaxf(a2, 0.f);
    }
    __syncthreads();
    if (tid == 0) {
        float o = po_b[0];
        #pragma unroll
        for (int i = 0; i < 10; ++i) o += pol[i] * po_w[i];
        out[b] = o;
    }
}

extern "C" void kernel_launch(void* const* d_in, const int* in_sizes, int n_in,
                              void* d_out, int out_size, void* d_ws, size_t ws_size,
                              hipStream_t stream)
{
    const float* x       = (const float*)d_in[0];
    const float* eattr   = (const float*)d_in[1];
    const int*   eidx    = (const int*)d_in[2];
    const int*   batch   = (const int*)d_in[3];
    const float* action  = (const float*)d_in[4];
    const float* node_w  = (const float*)d_in[5];
    const float* node_b  = (const float*)d_in[6];
    const float* edge_w  = (const float*)d_in[7];
    const float* edge_b  = (const float*)d_in[8];
    const float* tArr    = (const float*)d_in[9];
    const float* mlp_w1  = (const float*)d_in[10];
    const float* mlp_b1  = (const float*)d_in[11];
    const float* mlp_g1  = (const float*)d_in[12];
    const float* mlp_be1 = (const float*)d_in[13];
    const float* mlp_w2  = (const float*)d_in[14];
    const float* mlp_b2  = (const float*)d_in[15];
    const float* ln_g    = (const float*)d_in[16];
    const float* ln_b    = (const float*)d_in[17];
    const float* pin_w   = (const float*)d_in[18];
    const float* pin_b   = (const float*)d_in[19];
    const float* ph_w    = (const float*)d_in[20];
    const float* ph_b    = (const float*)d_in[21];
    const float* po_w    = (const float*)d_in[22];
    const float* po_b    = (const float*)d_in[23];
    float* out = (float*)d_out;

    char* ws = (char*)d_ws;
    float* h      = (float*)ws;                                  // N*16
    float* y      = h + (size_t)N_NODES * HID;                   // N*16
    float* aggr   = y + (size_t)N_NODES * HID;                   // N*16
    int*   cnt    = (int*)(aggr + (size_t)N_NODES * HID);        // N
    int*   rowptr = cnt + N_NODES;                               // N+1
    int*   bsum   = rowptr + N_NODES + 1;                        // NSCAN_BLK
    int*   offs   = bsum + NSCAN_BLK;                            // NSCAN_BLK
    int*   csr    = offs + NSCAN_BLK + 1;                        // E (v0 / binTot+binStart)
    float* gmax   = (float*)(csr + N_EDGES);                     // 64*16
    float* gsum   = gmax + NB * HID;                             // 64*16
    float* gcnt   = gsum + NB * HID;                             // 64
    int*   srcP   = (int*)(gcnt + NB);                           // E
    __half* eaPh  = (__half*)(srcP + N_EDGES);                   // E*16 half
    __half* partE = eaPh + (size_t)N_EDGES * HID;                // E*16 half
    const size_t need = (size_t)((char*)(partE + (size_t)N_EDGES * HID) - ws);
    const bool fast = (ws_size >= need);
    (void)in_sizes; (void)n_in; (void)out_size;

    // fast-path overlays (regions dead during CSR build):
    int* histG    = (int*)h;               // NPBLK*NBIN = 1MB
    int* boffsG   = histG + NPBLK * NBIN;  // 1MB (h = 6.4MB: fits)
    int* partDS   = (int*)y;               // E ints = 6.4MB
    int* binTot   = csr;                   // NBIN
    int* binStart = csr + NBIN;            // NBIN+1

    const int* srcA = eidx;
    const int* dstA = eidx + N_EDGES;

    if (fast) {
        // ---- binned CSR build, edge-MLP fused into partition pass ----
        k_hist1<<<NPBLK, 256, 0, stream>>>(dstA, histG);
        k_scanblk<<<NBIN, NPBLK, 0, stream>>>(histG, boffsG, binTot);
        k_scanbin<<<1, NBIN, 0, stream>>>(binTot, binStart);
        k_part2<<<NPBLK, 256, 0, stream>>>(dstA, srcA, eattr, edge_w, edge_b,
            boffsG, binStart, partDS, partE);
        k_finish<<<NBIN, 512, 0, stream>>>(partDS, partE, binStart, rowptr,
            srcP, eaPh);
        // ---- layers ----
        k_embed<<<N_NODES / 16, 256, 0, stream>>>(x, node_w, node_b, y);
        const int gridA = (16 * N_NODES + 255) / 256;
        const int gridN = (N_NODES + 255) / 256;
        for (int l = 0; l < NL; ++l) {
            const int nidx = (l < 3) ? (l + 1) : 0;
            k_aggr<<<gridA, 256, 0, stream>>>(y, rowptr, srcP, eaPh, tArr, l, aggr);
            k_node<<<gridN, 256, 0, stream>>>(y, h, aggr,
                mlp_w1 + l * 512, mlp_b1 + l * 32, mlp_g1 + l * 32, mlp_be1 + l * 32,
                mlp_w2 + l * 512, mlp_b2 + l * 16, ln_g + nidx * 16, ln_b + nidx * 16,
                h, y, l);
        }
        k_pool<<<NB, 256, 0, stream>>>(y, batch, gmax, gsum, gcnt);
    } else {
        // ---- v0 fallback (round-4 proven): atomic CSR + fused k_layer ----
        hipMemsetAsync(cnt, 0, (size_t)N_NODES * sizeof(int), stream);
        k_count<<<(N_EDGES + 255) / 256, 256, 0, stream>>>(dstA, cnt);
        k_scan1<<<NSCAN_BLK, 256, 0, stream>>>(cnt, rowptr, bsum);
        k_scan2<<<1, 512, 0, stream>>>(bsum, offs, rowptr);
        k_scan3<<<NSCAN_BLK, 256, 0, stream>>>(rowptr, offs, cnt);
        k_fill<<<(N_EDGES + 255) / 256, 256, 0, stream>>>(dstA, rowptr, cnt, csr);
        float* yA = y;
        float* yB = aggr;
        k_embed<<<N_NODES / 16, 256, 0, stream>>>(x, node_w, node_b, yA);
        const int grid = (4 * N_NODES + 255) / 256;
        for (int l = 0; l < NL; ++l) {
            const float* yin = (l & 1) ? yB : yA;
            float* yout      = (l & 1) ? yA : yB;
            const int nidx = (l < 3) ? (l + 1) : 0;
            k_layer<<<grid, 256, 0, stream>>>(
                yin, h, rowptr, csr, srcA, eattr, edge_w, edge_b, tArr, l,
                mlp_w1 + l * 512, mlp_b1 + l * 32, mlp_g1 + l * 32, mlp_be1 + l * 32,
                mlp_w2 + l * 512, mlp_b2 + l * 16, ln_g + nidx * 16, ln_b + nidx * 16,
                h, yout);
        }
        k_pool<<<NB, 256, 0, stream>>>(yA, batch, gmax, gsum, gcnt);
    }
    k_final<<<NB, 128, 0, stream>>>(gmax, gsum, gcnt, action,
        pin_w, pin_b, ph_w, ph_b, po_w, po_b, out);
}

// Round 11
// 426.776 us; speedup vs baseline: 1.6077x; 1.6077x over previous
//
#include <hip/hip_runtime.h>
#include <hip/hip_fp16.h>

#define N_NODES 100000
#define N_EDGES 1600000
#define NB 64
#define F_INn 64
#define HID 16
#define NL 4
#define NSCAN_BLK 391   // ceil(N_NODES/256) (fallback path)
#define NBIN 256
#define BINW 391        // ceil(100000/256); 391*256 = 100096 >= N
#define NPBLK 256

__device__ __forceinline__ unsigned pack2h(float a, float b) {
    __half2 h = __floats2half2_rn(a, b);
    return *reinterpret_cast<unsigned*>(&h);
}

__device__ __forceinline__ void blk_range(int blk, int& e0, int& e1) {
    e0 = (int)(((long long)blk * N_EDGES) / NPBLK);
    e1 = (int)(((long long)(blk + 1) * N_EDGES) / NPBLK);
}

// ---------------- node embedding: y0 = x @ node_w + node_b ----------------
__global__ __launch_bounds__(256) void k_embed(
    const float* __restrict__ x, const float* __restrict__ nw,
    const float* __restrict__ nb, float* __restrict__ yout)
{
    __shared__ float xs[16 * 64];
    __shared__ float Wn[64 * 16];
    __shared__ float Bn[16];
    const int tid = threadIdx.x;
    for (int i = tid; i < 1024; i += 256) Wn[i] = nw[i];
    if (tid < 16) Bn[tid] = nb[tid];
    const int n0 = blockIdx.x * 16;
    reinterpret_cast<float4*>(xs)[tid] =
        reinterpret_cast<const float4*>(x + (size_t)n0 * F_INn)[tid];
    __syncthreads();
    const int nl = tid >> 4, j = tid & 15;
    float acc = Bn[j];
    #pragma unroll 8
    for (int k = 0; k < 64; ++k) acc += xs[nl * 64 + k] * Wn[k * 16 + j];
    yout[(size_t)(n0 + nl) * HID + j] = acc;
}

// ---------------- edge MLP in ORIGINAL edge order: fully coalesced --------
__global__ __launch_bounds__(256) void k_edgemlp(
    const float* __restrict__ eattr, const float* __restrict__ ew,
    const float* __restrict__ ebv, __half* __restrict__ eaE)
{
    __shared__ float EW[256];
    __shared__ float EB[16];
    const int tid = threadIdx.x;
    EW[tid] = ew[tid];
    if (tid < 16) EB[tid] = ebv[tid];
    __syncthreads();
    const int e = blockIdx.x * 256 + tid;   // E divisible by 256
    float acc[16];
    #pragma unroll
    for (int j = 0; j < 16; ++j) acc[j] = EB[j];
    const float4* ag = reinterpret_cast<const float4*>(eattr + ((size_t)e << 4));
    #pragma unroll
    for (int q = 0; q < 4; ++q) {
        const float4 av = ag[q];
        #pragma unroll
        for (int j = 0; j < 16; ++j) {
            acc[j] += av.x * EW[(q * 4 + 0) * 16 + j];
            acc[j] += av.y * EW[(q * 4 + 1) * 16 + j];
            acc[j] += av.z * EW[(q * 4 + 2) * 16 + j];
            acc[j] += av.w * EW[(q * 4 + 3) * 16 + j];
        }
    }
    uint4 lo, hi;
    lo.x = pack2h(acc[0], acc[1]);   lo.y = pack2h(acc[2], acc[3]);
    lo.z = pack2h(acc[4], acc[5]);   lo.w = pack2h(acc[6], acc[7]);
    hi.x = pack2h(acc[8], acc[9]);   hi.y = pack2h(acc[10], acc[11]);
    hi.z = pack2h(acc[12], acc[13]); hi.w = pack2h(acc[14], acc[15]);
    uint4* eo = reinterpret_cast<uint4*>(eaE) + ((size_t)e << 1);
    eo[0] = lo;
    eo[1] = hi;
}

// ================= binned CSR build: keys only (8B), no payload ===========
__global__ __launch_bounds__(256) void k_hist1(
    const int* __restrict__ dstA, int* __restrict__ histG)
{
    __shared__ int h[NBIN];
    const int tid = threadIdx.x, blk = blockIdx.x;
    for (int t = tid; t < NBIN; t += 256) h[t] = 0;
    __syncthreads();
    int e0, e1; blk_range(blk, e0, e1);
    for (int e = e0 + tid; e < e1; e += 256)
        atomicAdd(&h[dstA[e] / BINW], 1);
    __syncthreads();
    for (int t = tid; t < NBIN; t += 256) histG[blk * NBIN + t] = h[t];
}

__global__ __launch_bounds__(NPBLK) void k_scanblk(
    const int* __restrict__ histG, int* __restrict__ boffsG,
    int* __restrict__ binTot)
{
    __shared__ int sc[NPBLK];
    const int tid = threadIdx.x, bin = blockIdx.x;
    const int v = histG[tid * NBIN + bin];
    sc[tid] = v;
    __syncthreads();
    for (int off = 1; off < NPBLK; off <<= 1) {
        int t = (tid >= off) ? sc[tid - off] : 0;
        __syncthreads();
        sc[tid] += t;
        __syncthreads();
    }
    boffsG[tid * NBIN + bin] = sc[tid] - v;
    if (tid == NPBLK - 1) binTot[bin] = sc[tid];
}

__global__ __launch_bounds__(NBIN) void k_scanbin(
    const int* __restrict__ binTot, int* __restrict__ binStart)
{
    __shared__ int sc[NBIN];
    const int tid = threadIdx.x;
    const int v = binTot[tid];
    sc[tid] = v;
    __syncthreads();
    for (int off = 1; off < NBIN; off <<= 1) {
        int t = (tid >= off) ? sc[tid - off] : 0;
        __syncthreads();
        sc[tid] += t;
        __syncthreads();
    }
    binStart[tid] = sc[tid] - v;
    if (tid == NBIN - 1) binStart[NBIN] = sc[tid];
}

// partition keys: partK[p] = {src, (dloc<<21)|e}  (dloc<512, e<2^21)
__global__ __launch_bounds__(256) void k_partl(
    const int* __restrict__ dstA, const int* __restrict__ srcA,
    const int* __restrict__ boffsG, const int* __restrict__ binStart,
    int2* __restrict__ partK)
{
    __shared__ int cur[NBIN];
    const int tid = threadIdx.x, blk = blockIdx.x;
    for (int t = tid; t < NBIN; t += 256)
        cur[t] = binStart[t] + boffsG[blk * NBIN + t];
    __syncthreads();
    int e0, e1; blk_range(blk, e0, e1);
    for (int e = e0 + tid; e < e1; e += 256) {
        const int d = dstA[e];
        const int bin = d / BINW;
        const int dloc = d - bin * BINW;
        const int p = atomicAdd(&cur[bin], 1);
        partK[p] = make_int2(srcA[e], (dloc << 21) | e);
    }
}

// fused per-bin: count + scan -> rowptr, then place srcP/csrE (4B each)
__global__ __launch_bounds__(512) void k_finishl(
    const int2* __restrict__ partK, const int* __restrict__ binStart,
    int* __restrict__ rowptr, int* __restrict__ srcP, int* __restrict__ csrE)
{
    __shared__ int h[BINW];
    __shared__ int sc[512];
    __shared__ int cur[BINW];
    const int tid = threadIdx.x, bin = blockIdx.x;
    const int base = bin * BINW;
    for (int t = tid; t < BINW; t += 512) h[t] = 0;
    __syncthreads();
    const int i0 = binStart[bin], i1 = binStart[bin + 1];
    for (int i = i0 + tid; i < i1; i += 512)
        atomicAdd(&h[partK[i].y >> 21], 1);
    __syncthreads();
    const int v = (tid < BINW) ? h[tid] : 0;
    sc[tid] = v;
    __syncthreads();
    for (int off = 1; off < 512; off <<= 1) {
        int t = (tid >= off) ? sc[tid - off] : 0;
        __syncthreads();
        sc[tid] += t;
        __syncthreads();
    }
    if (tid < BINW) {
        const int r = i0 + sc[tid] - v;
        const int idx = base + tid;
        if (idx < N_NODES) rowptr[idx] = r;
        cur[tid] = r;
    }
    if (bin == NBIN - 1 && tid == 0) rowptr[N_NODES] = N_EDGES;
    __syncthreads();
    for (int i = i0 + tid; i < i1; i += 512) {
        const int2 w = partK[i];
        const int dloc = w.y >> 21;
        const int p = atomicAdd(&cur[dloc], 1);
        srcP[p] = w.x;
        csrE[p] = w.y & 0x1FFFFF;
    }
}

// ---------------- v0 fallback CSR build pieces ----------------
__global__ __launch_bounds__(256) void k_count(
    const int* __restrict__ dstA, int* __restrict__ cnt)
{
    const int e = blockIdx.x * 256 + threadIdx.x;
    if (e < N_EDGES) atomicAdd(cnt + dstA[e], 1);
}

__global__ __launch_bounds__(256) void k_scan1(
    const int* __restrict__ cnt, int* __restrict__ rowptr, int* __restrict__ bsum)
{
    __shared__ int sc[256];
    const int tid = threadIdx.x;
    const int i = blockIdx.x * 256 + tid;
    const int v = (i < N_NODES) ? cnt[i] : 0;
    sc[tid] = v;
    __syncthreads();
    for (int off = 1; off < 256; off <<= 1) {
        int t = (tid >= off) ? sc[tid - off] : 0;
        __syncthreads();
        sc[tid] += t;
        __syncthreads();
    }
    if (i < N_NODES) rowptr[i] = sc[tid] - v;
    if (tid == 255) bsum[blockIdx.x] = sc[tid];
}

__global__ __launch_bounds__(512) void k_scan2(
    const int* __restrict__ bsum, int* __restrict__ offs, int* __restrict__ rowptr)
{
    __shared__ int sc[512];
    const int tid = threadIdx.x;
    const int v = (tid < NSCAN_BLK) ? bsum[tid] : 0;
    sc[tid] = v;
    __syncthreads();
    for (int off = 1; off < 512; off <<= 1) {
        int t = (tid >= off) ? sc[tid - off] : 0;
        __syncthreads();
        sc[tid] += t;
        __syncthreads();
    }
    if (tid < NSCAN_BLK) offs[tid] = sc[tid] - v;
    if (tid == NSCAN_BLK - 1) rowptr[N_NODES] = sc[tid];
}

__global__ __launch_bounds__(256) void k_scan3(
    int* __restrict__ rowptr, const int* __restrict__ offs, int* __restrict__ cnt)
{
    const int i = blockIdx.x * 256 + threadIdx.x;
    if (i < N_NODES) {
        rowptr[i] += offs[i >> 8];
        cnt[i] = 0;
    }
}

__global__ __launch_bounds__(256) void k_fill(
    const int* __restrict__ dstA, const int* __restrict__ rowptr,
    int* __restrict__ cnt, int* __restrict__ csr)
{
    const int e = blockIdx.x * 256 + threadIdx.x;
    if (e >= N_EDGES) return;
    const int d = dstA[e];
    const int pos = atomicAdd(cnt + d, 1);
    csr[rowptr[d] + pos] = e;
}

// ---------------- per-layer aggregation: 16 lanes/node, fp16 ea gather ---
__global__ __launch_bounds__(256, 8) void k_aggr(
    const float* __restrict__ yin, const int* __restrict__ rowptr,
    const int* __restrict__ srcP, const int* __restrict__ csrE,
    const __half* __restrict__ eaE, const float* __restrict__ tArr,
    int layer, float* __restrict__ aggr)
{
    const int t = blockIdx.x * 256 + threadIdx.x;
    const int n = t >> 4;
    if (n >= N_NODES) return;
    const int sub = threadIdx.x & 15;
    const int es = sub >> 2, cg = sub & 3;
    const int row0 = rowptr[n], row1 = rowptr[n + 1];
    const float tv = tArr[layer];

    float4 s = make_float4(0.f, 0.f, 0.f, 0.f);
    float4 num = make_float4(0.f, 0.f, 0.f, 0.f);

    int i = row0 + es;
    bool has = (i < row1);
    int spn = 0;
    uint2 ean = make_uint2(0u, 0u);
    if (has) {
        spn = srcP[i];
        const int en = csrE[i];
        ean = reinterpret_cast<const uint2*>(eaE + ((size_t)en << 4))[cg];
    }
    while (has) {
        const int sp = spn;
        const uint2 eaw = ean;
        const int i2 = i + 4;
        const bool has2 = (i2 < row1);
        if (has2) {
            spn = srcP[i2];
            const int en2 = csrE[i2];
            ean = reinterpret_cast<const uint2*>(eaE + ((size_t)en2 << 4))[cg];
        }
        const float4 yv = reinterpret_cast<const float4*>(yin + ((size_t)sp << 4))[cg];
        const float2 f0 = __half22float2(*reinterpret_cast<const __half2*>(&eaw.x));
        const float2 f1 = __half22float2(*reinterpret_cast<const __half2*>(&eaw.y));
        float m, ez;
        m = fmaxf(yv.x + f0.x, 0.f) + 1e-7f; ez = __expf(tv * m); s.x += ez; num.x += m * ez;
        m = fmaxf(yv.y + f0.y, 0.f) + 1e-7f; ez = __expf(tv * m); s.y += ez; num.y += m * ez;
        m = fmaxf(yv.z + f1.x, 0.f) + 1e-7f; ez = __expf(tv * m); s.z += ez; num.z += m * ez;
        m = fmaxf(yv.w + f1.y, 0.f) + 1e-7f; ez = __expf(tv * m); s.w += ez; num.w += m * ez;
        i = i2; has = has2;
    }
    s.x += __shfl_xor(s.x, 4); s.y += __shfl_xor(s.y, 4);
    s.z += __shfl_xor(s.z, 4); s.w += __shfl_xor(s.w, 4);
    num.x += __shfl_xor(num.x, 4); num.y += __shfl_xor(num.y, 4);
    num.z += __shfl_xor(num.z, 4); num.w += __shfl_xor(num.w, 4);
    s.x += __shfl_xor(s.x, 8); s.y += __shfl_xor(s.y, 8);
    s.z += __shfl_xor(s.z, 8); s.w += __shfl_xor(s.w, 8);
    num.x += __shfl_xor(num.x, 8); num.y += __shfl_xor(num.y, 8);
    num.z += __shfl_xor(num.z, 8); num.w += __shfl_xor(num.w, 8);
    if (es == 0) {
        float4 r;
        r.x = num.x / (s.x + 1e-16f);
        r.y = num.y / (s.y + 1e-16f);
        r.z = num.z / (s.z + 1e-16f);
        r.w = num.w / (s.w + 1e-16f);
        reinterpret_cast<float4*>(aggr + ((size_t)n << 4))[cg] = r;
    }
}

// ---------------- node pass: MLP + residual + next-norm ----------------
__global__ __launch_bounds__(256) void k_node(
    const float* __restrict__ yin, const float* __restrict__ hprev,
    const float* __restrict__ aggr,
    const float* __restrict__ w1, const float* __restrict__ b1,
    const float* __restrict__ g1, const float* __restrict__ be1,
    const float* __restrict__ w2, const float* __restrict__ b2,
    const float* __restrict__ gn, const float* __restrict__ bn,
    float* __restrict__ hout, float* __restrict__ yout, int layer)
{
    __shared__ float4 W1[128];
    __shared__ float4 W2[128];
    __shared__ float B1[32], G1[32], BE1[32], B2[16], GN[16], BN[16];
    const int tid = threadIdx.x;
    if (tid < 128) {
        W1[tid] = reinterpret_cast<const float4*>(w1)[tid];
        W2[tid] = reinterpret_cast<const float4*>(w2)[tid];
    }
    if (tid < 32) { B1[tid] = b1[tid]; G1[tid] = g1[tid]; BE1[tid] = be1[tid]; }
    if (tid < 16) { B2[tid] = b2[tid]; GN[tid] = gn[tid]; BN[tid] = bn[tid]; }
    __syncthreads();
    const int n = blockIdx.x * 256 + tid;
    if (n >= N_NODES) return;
    const size_t base = (size_t)n * HID;

    float hin[16];
    {
        const float4* yg = reinterpret_cast<const float4*>(yin + base);
        const float4* ag = reinterpret_cast<const float4*>(aggr + base);
        #pragma unroll
        for (int q = 0; q < 4; ++q) {
            float4 yv = yg[q], av = ag[q];
            hin[q * 4 + 0] = yv.x + av.x;
            hin[q * 4 + 1] = yv.y + av.y;
            hin[q * 4 + 2] = yv.z + av.z;
            hin[q * 4 + 3] = yv.w + av.w;
        }
    }
    float z[32];
    #pragma unroll
    for (int i = 0; i < 32; ++i) z[i] = B1[i];
    #pragma unroll
    for (int j = 0; j < 16; ++j) {
        const float hv = hin[j];
        #pragma unroll
        for (int q = 0; q < 8; ++q) {
            float4 w = W1[j * 8 + q];
            z[q * 4 + 0] += hv * w.x; z[q * 4 + 1] += hv * w.y;
            z[q * 4 + 2] += hv * w.z; z[q * 4 + 3] += hv * w.w;
        }
    }
    float mu = 0.f;
    #pragma unroll
    for (int i = 0; i < 32; ++i) mu += z[i];
    mu *= (1.f / 32.f);
    float var = 0.f;
    #pragma unroll
    for (int i = 0; i < 32; ++i) { float d = z[i] - mu; var += d * d; }
    var *= (1.f / 32.f);
    const float rs = rsqrtf(var + 1e-5f);

    float o[16];
    #pragma unroll
    for (int j = 0; j < 16; ++j) o[j] = B2[j];
    #pragma unroll
    for (int i = 0; i < 32; ++i) {
        const float r = fmaxf((z[i] - mu) * rs * G1[i] + BE1[i], 0.f);
        #pragma unroll
        for (int q = 0; q < 4; ++q) {
            float4 w = W2[i * 4 + q];
            o[q * 4 + 0] += r * w.x; o[q * 4 + 1] += r * w.y;
            o[q * 4 + 2] += r * w.z; o[q * 4 + 3] += r * w.w;
        }
    }
    float hn[16];
    if (layer == 0) {
        #pragma unroll
        for (int j = 0; j < 16; ++j) hn[j] = o[j];
    } else {
        const float4* hg = reinterpret_cast<const float4*>(hprev + base);
        float hr[16];
        *reinterpret_cast<float4*>(&hr[0])  = hg[0];
        *reinterpret_cast<float4*>(&hr[4])  = hg[1];
        *reinterpret_cast<float4*>(&hr[8])  = hg[2];
        *reinterpret_cast<float4*>(&hr[12]) = hg[3];
        #pragma unroll
        for (int j = 0; j < 16; ++j) hn[j] = hr[j] + o[j];
    }
    {
        float4* ho = reinterpret_cast<float4*>(hout + base);
        #pragma unroll
        for (int q = 0; q < 4; ++q)
            ho[q] = make_float4(hn[q*4+0], hn[q*4+1], hn[q*4+2], hn[q*4+3]);
    }
    float mu2 = 0.f;
    #pragma unroll
    for (int j = 0; j < 16; ++j) mu2 += hn[j];
    mu2 *= (1.f / 16.f);
    float v2 = 0.f;
    #pragma unroll
    for (int j = 0; j < 16; ++j) { float d = hn[j] - mu2; v2 += d * d; }
    v2 *= (1.f / 16.f);
    const float rs2 = rsqrtf(v2 + 1e-5f);
    float yn[16];
    #pragma unroll
    for (int j = 0; j < 16; ++j)
        yn[j] = fmaxf((hn[j] - mu2) * rs2 * GN[j] + BN[j], 0.f);
    {
        float4* yo = reinterpret_cast<float4*>(yout + base);
        #pragma unroll
        for (int q = 0; q < 4; ++q)
            yo[q] = make_float4(yn[q*4+0], yn[q*4+1], yn[q*4+2], yn[q*4+3]);
    }
}

// ---------------- v0 FALLBACK fused layer (round-4, proven) --------------
__global__ __launch_bounds__(256) void k_layer(
    const float* __restrict__ yin, const float* __restrict__ hprev,
    const int* __restrict__ rowptr, const int* __restrict__ csr,
    const int* __restrict__ srcA, const float* __restrict__ eattr,
    const float* __restrict__ ew, const float* __restrict__ ebv,
    const float* __restrict__ tArr, int layer,
    const float* __restrict__ w1, const float* __restrict__ b1,
    const float* __restrict__ g1, const float* __restrict__ be1,
    const float* __restrict__ w2, const float* __restrict__ b2,
    const float* __restrict__ gn, const float* __restrict__ bn,
    float* __restrict__ hout, float* __restrict__ yout)
{
    __shared__ float EW[256];
    __shared__ float EB[16];
    __shared__ float4 W1[128];
    __shared__ float4 W2[128];
    __shared__ float B1[32], G1[32], BE1[32], B2[16], GN[16], BN[16];
    const int tid = threadIdx.x;
    EW[tid] = ew[tid];
    if (tid < 128) {
        W1[tid] = reinterpret_cast<const float4*>(w1)[tid];
        W2[tid] = reinterpret_cast<const float4*>(w2)[tid];
    }
    if (tid < 32) { B1[tid] = b1[tid]; G1[tid] = g1[tid]; BE1[tid] = be1[tid]; }
    if (tid < 16) { EB[tid] = ebv[tid]; B2[tid] = b2[tid]; GN[tid] = gn[tid]; BN[tid] = bn[tid]; }
    __syncthreads();

    const int t = blockIdx.x * 256 + tid;
    const int n = t >> 2, sub = t & 3;
    if (n >= N_NODES) return;
    const int row0 = rowptr[n], row1 = rowptr[n + 1];
    const float tv = tArr[layer];

    float s[16], num[16];
    #pragma unroll
    for (int j = 0; j < 16; ++j) { s[j] = 0.f; num[j] = 0.f; }

    for (int i = row0 + sub; i < row1; i += 4) {
        const int eid = csr[i];
        const int sp = srcA[eid];
        float a[16], yv[16];
        {
            const float4* ag = reinterpret_cast<const float4*>(eattr + (size_t)eid * 16);
            *reinterpret_cast<float4*>(&a[0])  = ag[0];
            *reinterpret_cast<float4*>(&a[4])  = ag[1];
            *reinterpret_cast<float4*>(&a[8])  = ag[2];
            *reinterpret_cast<float4*>(&a[12]) = ag[3];
            const float4* yg = reinterpret_cast<const float4*>(yin + (size_t)sp * 16);
            *reinterpret_cast<float4*>(&yv[0])  = yg[0];
            *reinterpret_cast<float4*>(&yv[4])  = yg[1];
            *reinterpret_cast<float4*>(&yv[8])  = yg[2];
            *reinterpret_cast<float4*>(&yv[12]) = yg[3];
        }
        float acc[16];
        #pragma unroll
        for (int j = 0; j < 16; ++j) acc[j] = EB[j];
        #pragma unroll
        for (int k = 0; k < 16; ++k) {
            const float av = a[k];
            #pragma unroll
            for (int j = 0; j < 16; ++j) acc[j] += av * EW[k * 16 + j];
        }
        #pragma unroll
        for (int j = 0; j < 16; ++j) {
            float m = fmaxf(yv[j] + acc[j], 0.f) + 1e-7f;
            float ez = __expf(tv * m);
            s[j] += ez;
            num[j] += m * ez;
        }
    }
    #pragma unroll
    for (int j = 0; j < 16; ++j) {
        s[j]   += __shfl_xor(s[j], 1);   num[j] += __shfl_xor(num[j], 1);
        s[j]   += __shfl_xor(s[j], 2);   num[j] += __shfl_xor(num[j], 2);
    }
    if (sub != 0) return;

    const size_t base = (size_t)n * HID;
    float hin[16];
    {
        const float4* yg = reinterpret_cast<const float4*>(yin + base);
        float yr[16];
        *reinterpret_cast<float4*>(&yr[0])  = yg[0];
        *reinterpret_cast<float4*>(&yr[4])  = yg[1];
        *reinterpret_cast<float4*>(&yr[8])  = yg[2];
        *reinterpret_cast<float4*>(&yr[12]) = yg[3];
        #pragma unroll
        for (int j = 0; j < 16; ++j) hin[j] = yr[j] + num[j] / (s[j] + 1e-16f);
    }
    float z[32];
    #pragma unroll
    for (int i = 0; i < 32; ++i) z[i] = B1[i];
    #pragma unroll
    for (int j = 0; j < 16; ++j) {
        const float hv = hin[j];
        #pragma unroll
        for (int q = 0; q < 8; ++q) {
            float4 w = W1[j * 8 + q];
            z[q * 4 + 0] += hv * w.x; z[q * 4 + 1] += hv * w.y;
            z[q * 4 + 2] += hv * w.z; z[q * 4 + 3] += hv * w.w;
        }
    }
    float mu = 0.f;
    #pragma unroll
    for (int i = 0; i < 32; ++i) mu += z[i];
    mu *= (1.f / 32.f);
    float var = 0.f;
    #pragma unroll
    for (int i = 0; i < 32; ++i) { float d = z[i] - mu; var += d * d; }
    var *= (1.f / 32.f);
    const float rs = rsqrtf(var + 1e-5f);

    float o[16];
    #pragma unroll
    for (int j = 0; j < 16; ++j) o[j] = B2[j];
    #pragma unroll
    for (int i = 0; i < 32; ++i) {
        const float r = fmaxf((z[i] - mu) * rs * G1[i] + BE1[i], 0.f);
        #pragma unroll
        for (int q = 0; q < 4; ++q) {
            float4 w = W2[i * 4 + q];
            o[q * 4 + 0] += r * w.x; o[q * 4 + 1] += r * w.y;
            o[q * 4 + 2] += r * w.z; o[q * 4 + 3] += r * w.w;
        }
    }
    float hn[16];
    if (layer == 0) {
        #pragma unroll
        for (int j = 0; j < 16; ++j) hn[j] = o[j];
    } else {
        const float4* hg = reinterpret_cast<const float4*>(hprev + base);
        float hr[16];
        *reinterpret_cast<float4*>(&hr[0])  = hg[0];
        *reinterpret_cast<float4*>(&hr[4])  = hg[1];
        *reinterpret_cast<float4*>(&hr[8])  = hg[2];
        *reinterpret_cast<float4*>(&hr[12]) = hg[3];
        #pragma unroll
        for (int j = 0; j < 16; ++j) hn[j] = hr[j] + o[j];
    }
    {
        float4* ho = reinterpret_cast<float4*>(hout + base);
        #pragma unroll
        for (int q = 0; q < 4; ++q)
            ho[q] = make_float4(hn[q*4+0], hn[q*4+1], hn[q*4+2], hn[q*4+3]);
    }
    float mu2 = 0.f;
    #pragma unroll
    for (int j = 0; j < 16; ++j) mu2 += hn[j];
    mu2 *= (1.f / 16.f);
    float v2 = 0.f;
    #pragma unroll
    for (int j = 0; j < 16; ++j) { float d = hn[j] - mu2; v2 += d * d; }
    v2 *= (1.f / 16.f);
    const float rs2 = rsqrtf(v2 + 1e-5f);
    float yn[16];
    #pragma unroll
    for (int j = 0; j < 16; ++j)
        yn[j] = fmaxf((hn[j] - mu2) * rs2 * GN[j] + BN[j], 0.f);
    {
        float4* yo = reinterpret_cast<float4*>(yout + base);
        #pragma unroll
        for (int q = 0; q < 4; ++q)
            yo[q] = make_float4(yn[q*4+0], yn[q*4+1], yn[q*4+2], yn[q*4+3]);
    }
}

// ---------------- pooling: one block per graph, no atomics ----------------
__global__ __launch_bounds__(256) void k_pool(
    const float* __restrict__ y, const int* __restrict__ batch,
    float* __restrict__ gmax, float* __restrict__ gsum, float* __restrict__ gcnt)
{
    const int g = blockIdx.x;
    const int tid = threadIdx.x;
    int lo = 0, hi = N_NODES;
    while (lo < hi) { int mid = (lo + hi) >> 1; if (batch[mid] < g) lo = mid + 1; else hi = mid; }
    const int start = lo;
    lo = 0; hi = N_NODES;
    while (lo < hi) { int mid = (lo + hi) >> 1; if (batch[mid] < g + 1) lo = mid + 1; else hi = mid; }
    const int end = lo;

    const int ch = tid & 15, slot = tid >> 4;
    float mx = 0.f, sm = 0.f;
    for (int n = start + slot; n < end; n += 16) {
        float v = y[(size_t)n * HID + ch];
        mx = fmaxf(mx, v);
        sm += v;
    }
    __shared__ float rm[256], rsum[256];
    rm[tid] = mx; rsum[tid] = sm;
    __syncthreads();
    for (int off = 8; off >= 1; off >>= 1) {
        if (slot < off) {
            rm[tid] = fmaxf(rm[tid], rm[tid + off * 16]);
            rsum[tid] += rsum[tid + off * 16];
        }
        __syncthreads();
    }
    if (slot == 0) {
        gmax[g * HID + ch] = rm[ch];
        gsum[g * HID + ch] = rsum[ch];
        if (ch == 0) gcnt[g] = (float)(end - start);
    }
}

// ---------------- final MLP head ----------------
__global__ __launch_bounds__(128) void k_final(
    const float* __restrict__ gmax, const float* __restrict__ gsum,
    const float* __restrict__ gcnt, const float* __restrict__ action,
    const float* __restrict__ pin_w, const float* __restrict__ pin_b,
    const float* __restrict__ ph_w, const float* __restrict__ ph_b,
    const float* __restrict__ po_w, const float* __restrict__ po_b,
    float* __restrict__ out)
{
    __shared__ float mol[32];
    __shared__ float fpv[128];
    __shared__ float pol[10];
    const int b = blockIdx.x, tid = threadIdx.x;
    if (tid < 16) mol[tid] = gmax[b * 16 + tid];
    else if (tid < 32) mol[tid] = gsum[b * 16 + (tid - 16)] / gcnt[b];
    __syncthreads();
    float acc = pin_b[tid];
    #pragma unroll 4
    for (int k = 0; k < 32; ++k) acc += mol[k] * pin_w[k * 128 + tid];
    fpv[tid] = fmaxf(acc, 0.f);
    __syncthreads();
    if (tid < 10) {
        float a2 = ph_b[tid];
        for (int k = 0; k < 128; ++k) a2 += fpv[k] * ph_w[k * 10 + tid];
        #pragma unroll
        for (int k = 0; k < 6; ++k) a2 += action[b * 6 + k] * ph_w[(128 + k) * 10 + tid];
        pol[tid] = fmaxf(a2, 0.f);
    }
    __syncthreads();
    if (tid == 0) {
        float o = po_b[0];
        #pragma unroll
        for (int i = 0; i < 10; ++i) o += pol[i] * po_w[i];
        out[b] = o;
    }
}

extern "C" void kernel_launch(void* const* d_in, const int* in_sizes, int n_in,
                              void* d_out, int out_size, void* d_ws, size_t ws_size,
                              hipStream_t stream)
{
    const float* x       = (const float*)d_in[0];
    const float* eattr   = (const float*)d_in[1];
    const int*   eidx    = (const int*)d_in[2];
    const int*   batch   = (const int*)d_in[3];
    const float* action  = (const float*)d_in[4];
    const float* node_w  = (const float*)d_in[5];
    const float* node_b  = (const float*)d_in[6];
    const float* edge_w  = (const float*)d_in[7];
    const float* edge_b  = (const float*)d_in[8];
    const float* tArr    = (const float*)d_in[9];
    const float* mlp_w1  = (const float*)d_in[10];
    const float* mlp_b1  = (const float*)d_in[11];
    const float* mlp_g1  = (const float*)d_in[12];
    const float* mlp_be1 = (const float*)d_in[13];
    const float* mlp_w2  = (const float*)d_in[14];
    const float* mlp_b2  = (const float*)d_in[15];
    const float* ln_g    = (const float*)d_in[16];
    const float* ln_b    = (const float*)d_in[17];
    const float* pin_w   = (const float*)d_in[18];
    const float* pin_b   = (const float*)d_in[19];
    const float* ph_w    = (const float*)d_in[20];
    const float* ph_b    = (const float*)d_in[21];
    const float* po_w    = (const float*)d_in[22];
    const float* po_b    = (const float*)d_in[23];
    float* out = (float*)d_out;

    char* ws = (char*)d_ws;
    float* h      = (float*)ws;                                  // N*16
    float* y      = h + (size_t)N_NODES * HID;                   // N*16
    float* aggr   = y + (size_t)N_NODES * HID;                   // N*16
    int*   cnt    = (int*)(aggr + (size_t)N_NODES * HID);        // N
    int*   rowptr = cnt + N_NODES;                               // N+1
    int*   bsum   = rowptr + N_NODES + 1;                        // NSCAN_BLK
    int*   offs   = bsum + NSCAN_BLK;                            // NSCAN_BLK
    int*   csr    = offs + NSCAN_BLK + 1;                        // E (v0 / binTot+binStart)
    float* gmax   = (float*)(csr + N_EDGES);                     // 64*16
    float* gsum   = gmax + NB * HID;                             // 64*16
    float* gcnt   = gsum + NB * HID;                             // 64
    int*   srcP   = (int*)(gcnt + NB);                           // E
    int*   csrE   = srcP + N_EDGES;                              // E
    __half* eaE   = (__half*)(csrE + N_EDGES);                   // E*16 half
    const size_t need = (size_t)((char*)(eaE + (size_t)N_EDGES * HID) - ws);
    const bool fast = (ws_size >= need);
    (void)in_sizes; (void)n_in; (void)out_size;

    // fast-path overlays (regions dead during CSR build):
    int2* partK   = (int2*)h;              // E int2 = 12.8MB (h + y)
    int* histG    = (int*)aggr;            // NPBLK*NBIN = 256KB
    int* boffsG   = histG + NPBLK * NBIN;  // 256KB (aggr = 6.4MB: fits)
    int* binTot   = csr;                   // NBIN
    int* binStart = csr + NBIN;            // NBIN+1

    const int* srcA = eidx;
    const int* dstA = eidx + N_EDGES;

    if (fast) {
        // ---- key-only binned CSR build + edge-MLP in original order ----
        k_edgemlp<<<N_EDGES / 256, 256, 0, stream>>>(eattr, edge_w, edge_b, eaE);
        k_hist1<<<NPBLK, 256, 0, stream>>>(dstA, histG);
        k_scanblk<<<NBIN, NPBLK, 0, stream>>>(histG, boffsG, binTot);
        k_scanbin<<<1, NBIN, 0, stream>>>(binTot, binStart);
        k_partl<<<NPBLK, 256, 0, stream>>>(dstA, srcA, boffsG, binStart, partK);
        k_finishl<<<NBIN, 512, 0, stream>>>(partK, binStart, rowptr, srcP, csrE);
        // ---- layers ----
        k_embed<<<N_NODES / 16, 256, 0, stream>>>(x, node_w, node_b, y);
        const int gridA = (16 * N_NODES + 255) / 256;
        const int gridN = (N_NODES + 255) / 256;
        for (int l = 0; l < NL; ++l) {
            const int nidx = (l < 3) ? (l + 1) : 0;
            k_aggr<<<gridA, 256, 0, stream>>>(y, rowptr, srcP, csrE, eaE,
                tArr, l, aggr);
            k_node<<<gridN, 256, 0, stream>>>(y, h, aggr,
                mlp_w1 + l * 512, mlp_b1 + l * 32, mlp_g1 + l * 32, mlp_be1 + l * 32,
                mlp_w2 + l * 512, mlp_b2 + l * 16, ln_g + nidx * 16, ln_b + nidx * 16,
                h, y, l);
        }
        k_pool<<<NB, 256, 0, stream>>>(y, batch, gmax, gsum, gcnt);
    } else {
        // ---- v0 fallback (round-4 proven): atomic CSR + fused k_layer ----
        hipMemsetAsync(cnt, 0, (size_t)N_NODES * sizeof(int), stream);
        k_count<<<(N_EDGES + 255) / 256, 256, 0, stream>>>(dstA, cnt);
        k_scan1<<<NSCAN_BLK, 256, 0, stream>>>(cnt, rowptr, bsum);
        k_scan2<<<1, 512, 0, stream>>>(bsum, offs, rowptr);
        k_scan3<<<NSCAN_BLK, 256, 0, stream>>>(rowptr, offs, cnt);
        k_fill<<<(N_EDGES + 255) / 256, 256, 0, stream>>>(dstA, rowptr, cnt, csr);
        float* yA = y;
        float* yB = aggr;
        k_embed<<<N_NODES / 16, 256, 0, stream>>>(x, node_w, node_b, yA);
        const int grid = (4 * N_NODES + 255) / 256;
        for (int l = 0; l < NL; ++l) {
            const float* yin = (l & 1) ? yB : yA;
            float* yout      = (l & 1) ? yA : yB;
            const int nidx = (l < 3) ? (l + 1) : 0;
            k_layer<<<grid, 256, 0, stream>>>(
                yin, h, rowptr, csr, srcA, eattr, edge_w, edge_b, tArr, l,
                mlp_w1 + l * 512, mlp_b1 + l * 32, mlp_g1 + l * 32, mlp_be1 + l * 32,
                mlp_w2 + l * 512, mlp_b2 + l * 16, ln_g + nidx * 16, ln_b + nidx * 16,
                h, yout);
        }
        k_pool<<<NB, 256, 0, stream>>>(yA, batch, gmax, gsum, gcnt);
    }
    k_final<<<NB, 128, 0, stream>>>(gmax, gsum, gcnt, action,
        pin_w, pin_b, ph_w, ph_b, po_w, po_b, out);
}

// Round 12
// 377.902 us; speedup vs baseline: 1.8156x; 1.1293x over previous
//
#include <hip/hip_runtime.h>
#include <hip/hip_fp16.h>

#define N_NODES 100000
#define N_EDGES 1600000
#define NB 64
#define F_INn 64
#define HID 16
#define NL 4
#define NSCAN_BLK 391   // ceil(N_NODES/256) (fallback path)
#define NBIN 256
#define BINW 391        // ceil(100000/256); 391*256 = 100096 >= N
#define NPBLK 256

__device__ __forceinline__ unsigned pack2h(float a, float b) {
    __half2 h = __floats2half2_rn(a, b);
    return *reinterpret_cast<unsigned*>(&h);
}

__device__ __forceinline__ void blk_range(int blk, int& e0, int& e1) {
    e0 = (int)(((long long)blk * N_EDGES) / NPBLK);
    e1 = (int)(((long long)(blk + 1) * N_EDGES) / NPBLK);
}

// ---------------- node embedding: y0 = x @ node_w + node_b ----------------
__global__ __launch_bounds__(256) void k_embed(
    const float* __restrict__ x, const float* __restrict__ nw,
    const float* __restrict__ nb, float* __restrict__ yout)
{
    __shared__ float xs[16 * 64];
    __shared__ float Wn[64 * 16];
    __shared__ float Bn[16];
    const int tid = threadIdx.x;
    for (int i = tid; i < 1024; i += 256) Wn[i] = nw[i];
    if (tid < 16) Bn[tid] = nb[tid];
    const int n0 = blockIdx.x * 16;
    reinterpret_cast<float4*>(xs)[tid] =
        reinterpret_cast<const float4*>(x + (size_t)n0 * F_INn)[tid];
    __syncthreads();
    const int nl = tid >> 4, j = tid & 15;
    float acc = Bn[j];
    #pragma unroll 8
    for (int k = 0; k < 64; ++k) acc += xs[nl * 64 + k] * Wn[k * 16 + j];
    yout[(size_t)(n0 + nl) * HID + j] = acc;
}

// ---------------- edge MLP in ORIGINAL edge order: fully coalesced --------
__global__ __launch_bounds__(256) void k_edgemlp(
    const float* __restrict__ eattr, const float* __restrict__ ew,
    const float* __restrict__ ebv, __half* __restrict__ eaE)
{
    __shared__ float EW[256];
    __shared__ float EB[16];
    const int tid = threadIdx.x;
    EW[tid] = ew[tid];
    if (tid < 16) EB[tid] = ebv[tid];
    __syncthreads();
    const int e = blockIdx.x * 256 + tid;   // E divisible by 256
    float acc[16];
    #pragma unroll
    for (int j = 0; j < 16; ++j) acc[j] = EB[j];
    const float4* ag = reinterpret_cast<const float4*>(eattr + ((size_t)e << 4));
    #pragma unroll
    for (int q = 0; q < 4; ++q) {
        const float4 av = ag[q];
        #pragma unroll
        for (int j = 0; j < 16; ++j) {
            acc[j] += av.x * EW[(q * 4 + 0) * 16 + j];
            acc[j] += av.y * EW[(q * 4 + 1) * 16 + j];
            acc[j] += av.z * EW[(q * 4 + 2) * 16 + j];
            acc[j] += av.w * EW[(q * 4 + 3) * 16 + j];
        }
    }
    uint4 lo, hi;
    lo.x = pack2h(acc[0], acc[1]);   lo.y = pack2h(acc[2], acc[3]);
    lo.z = pack2h(acc[4], acc[5]);   lo.w = pack2h(acc[6], acc[7]);
    hi.x = pack2h(acc[8], acc[9]);   hi.y = pack2h(acc[10], acc[11]);
    hi.z = pack2h(acc[12], acc[13]); hi.w = pack2h(acc[14], acc[15]);
    uint4* eo = reinterpret_cast<uint4*>(eaE) + ((size_t)e << 1);
    eo[0] = lo;
    eo[1] = hi;
}

// ================= binned CSR build: keys only (8B) =======================
__global__ __launch_bounds__(256) void k_hist1(
    const int* __restrict__ dstA, int* __restrict__ histG)
{
    __shared__ int h[NBIN];
    const int tid = threadIdx.x, blk = blockIdx.x;
    for (int t = tid; t < NBIN; t += 256) h[t] = 0;
    __syncthreads();
    int e0, e1; blk_range(blk, e0, e1);
    for (int e = e0 + tid; e < e1; e += 256)
        atomicAdd(&h[dstA[e] / BINW], 1);
    __syncthreads();
    for (int t = tid; t < NBIN; t += 256) histG[blk * NBIN + t] = h[t];
}

__global__ __launch_bounds__(NPBLK) void k_scanblk(
    const int* __restrict__ histG, int* __restrict__ boffsG,
    int* __restrict__ binTot)
{
    __shared__ int sc[NPBLK];
    const int tid = threadIdx.x, bin = blockIdx.x;
    const int v = histG[tid * NBIN + bin];
    sc[tid] = v;
    __syncthreads();
    for (int off = 1; off < NPBLK; off <<= 1) {
        int t = (tid >= off) ? sc[tid - off] : 0;
        __syncthreads();
        sc[tid] += t;
        __syncthreads();
    }
    boffsG[tid * NBIN + bin] = sc[tid] - v;
    if (tid == NPBLK - 1) binTot[bin] = sc[tid];
}

__global__ __launch_bounds__(NBIN) void k_scanbin(
    const int* __restrict__ binTot, int* __restrict__ binStart)
{
    __shared__ int sc[NBIN];
    const int tid = threadIdx.x;
    const int v = binTot[tid];
    sc[tid] = v;
    __syncthreads();
    for (int off = 1; off < NBIN; off <<= 1) {
        int t = (tid >= off) ? sc[tid - off] : 0;
        __syncthreads();
        sc[tid] += t;
        __syncthreads();
    }
    binStart[tid] = sc[tid] - v;
    if (tid == NBIN - 1) binStart[NBIN] = sc[tid];
}

// partition keys: partK[p] = {src, (dloc<<21)|e}  (dloc<512, e<2^21)
__global__ __launch_bounds__(256) void k_partl(
    const int* __restrict__ dstA, const int* __restrict__ srcA,
    const int* __restrict__ boffsG, const int* __restrict__ binStart,
    int2* __restrict__ partK)
{
    __shared__ int cur[NBIN];
    const int tid = threadIdx.x, blk = blockIdx.x;
    for (int t = tid; t < NBIN; t += 256)
        cur[t] = binStart[t] + boffsG[blk * NBIN + t];
    __syncthreads();
    int e0, e1; blk_range(blk, e0, e1);
    for (int e = e0 + tid; e < e1; e += 256) {
        const int d = dstA[e];
        const int bin = d / BINW;
        const int dloc = d - bin * BINW;
        const int p = atomicAdd(&cur[bin], 1);
        partK[p] = make_int2(srcA[e], (dloc << 21) | e);
    }
}

// fused per-bin: count + scan -> rowptr; place srcP AND permute fp16 payload
__global__ __launch_bounds__(512) void k_finishl(
    const int2* __restrict__ partK, const __half* __restrict__ eaE,
    const int* __restrict__ binStart, int* __restrict__ rowptr,
    int* __restrict__ srcP, __half* __restrict__ eaPh)
{
    __shared__ int h[BINW];
    __shared__ int sc[512];
    __shared__ int cur[BINW];
    const int tid = threadIdx.x, bin = blockIdx.x;
    const int base = bin * BINW;
    for (int t = tid; t < BINW; t += 512) h[t] = 0;
    __syncthreads();
    const int i0 = binStart[bin], i1 = binStart[bin + 1];
    for (int i = i0 + tid; i < i1; i += 512)
        atomicAdd(&h[partK[i].y >> 21], 1);
    __syncthreads();
    const int v = (tid < BINW) ? h[tid] : 0;
    sc[tid] = v;
    __syncthreads();
    for (int off = 1; off < 512; off <<= 1) {
        int t = (tid >= off) ? sc[tid - off] : 0;
        __syncthreads();
        sc[tid] += t;
        __syncthreads();
    }
    if (tid < BINW) {
        const int r = i0 + sc[tid] - v;
        const int idx = base + tid;
        if (idx < N_NODES) rowptr[idx] = r;
        cur[tid] = r;
    }
    if (bin == NBIN - 1 && tid == 0) rowptr[N_NODES] = N_EDGES;
    __syncthreads();
    for (int i = i0 + tid; i < i1; i += 512) {
        const int2 w = partK[i];
        const int dloc = w.y >> 21;
        const int p = atomicAdd(&cur[dloc], 1);
        srcP[p] = w.x;
        const int e = w.y & 0x1FFFFF;
        const uint4* si = reinterpret_cast<const uint4*>(eaE) + ((size_t)e << 1);
        uint4* di = reinterpret_cast<uint4*>(eaPh) + ((size_t)p << 1);
        di[0] = si[0];
        di[1] = si[1];
    }
}

// ---------------- v0 fallback CSR build pieces ----------------
__global__ __launch_bounds__(256) void k_count(
    const int* __restrict__ dstA, int* __restrict__ cnt)
{
    const int e = blockIdx.x * 256 + threadIdx.x;
    if (e < N_EDGES) atomicAdd(cnt + dstA[e], 1);
}

__global__ __launch_bounds__(256) void k_scan1(
    const int* __restrict__ cnt, int* __restrict__ rowptr, int* __restrict__ bsum)
{
    __shared__ int sc[256];
    const int tid = threadIdx.x;
    const int i = blockIdx.x * 256 + tid;
    const int v = (i < N_NODES) ? cnt[i] : 0;
    sc[tid] = v;
    __syncthreads();
    for (int off = 1; off < 256; off <<= 1) {
        int t = (tid >= off) ? sc[tid - off] : 0;
        __syncthreads();
        sc[tid] += t;
        __syncthreads();
    }
    if (i < N_NODES) rowptr[i] = sc[tid] - v;
    if (tid == 255) bsum[blockIdx.x] = sc[tid];
}

__global__ __launch_bounds__(512) void k_scan2(
    const int* __restrict__ bsum, int* __restrict__ offs, int* __restrict__ rowptr)
{
    __shared__ int sc[512];
    const int tid = threadIdx.x;
    const int v = (tid < NSCAN_BLK) ? bsum[tid] : 0;
    sc[tid] = v;
    __syncthreads();
    for (int off = 1; off < 512; off <<= 1) {
        int t = (tid >= off) ? sc[tid - off] : 0;
        __syncthreads();
        sc[tid] += t;
        __syncthreads();
    }
    if (tid < NSCAN_BLK) offs[tid] = sc[tid] - v;
    if (tid == NSCAN_BLK - 1) rowptr[N_NODES] = sc[tid];
}

__global__ __launch_bounds__(256) void k_scan3(
    int* __restrict__ rowptr, const int* __restrict__ offs, int* __restrict__ cnt)
{
    const int i = blockIdx.x * 256 + threadIdx.x;
    if (i < N_NODES) {
        rowptr[i] += offs[i >> 8];
        cnt[i] = 0;
    }
}

__global__ __launch_bounds__(256) void k_fill(
    const int* __restrict__ dstA, const int* __restrict__ rowptr,
    int* __restrict__ cnt, int* __restrict__ csr)
{
    const int e = blockIdx.x * 256 + threadIdx.x;
    if (e >= N_EDGES) return;
    const int d = dstA[e];
    const int pos = atomicAdd(cnt + d, 1);
    csr[rowptr[d] + pos] = e;
}

// ---------------- per-layer aggregation: 16 lanes/node, fp16 ea stream ---
__global__ __launch_bounds__(256, 8) void k_aggr(
    const float* __restrict__ yin, const int* __restrict__ rowptr,
    const int* __restrict__ srcP, const __half* __restrict__ eaPh,
    const float* __restrict__ tArr, int layer, float* __restrict__ aggr)
{
    const int t = blockIdx.x * 256 + threadIdx.x;
    const int n = t >> 4;
    if (n >= N_NODES) return;
    const int sub = threadIdx.x & 15;
    const int es = sub >> 2, cg = sub & 3;
    const int row0 = rowptr[n], row1 = rowptr[n + 1];
    const float tv = tArr[layer];

    float4 s = make_float4(0.f, 0.f, 0.f, 0.f);
    float4 num = make_float4(0.f, 0.f, 0.f, 0.f);

    int i = row0 + es;
    bool has = (i < row1);
    int spn = 0;
    uint2 ean = make_uint2(0u, 0u);
    if (has) {
        spn = srcP[i];
        ean = reinterpret_cast<const uint2*>(eaPh + ((size_t)i << 4))[cg];
    }
    while (has) {
        const int sp = spn;
        const uint2 eaw = ean;
        const int i2 = i + 4;
        const bool has2 = (i2 < row1);
        if (has2) {
            spn = srcP[i2];
            ean = reinterpret_cast<const uint2*>(eaPh + ((size_t)i2 << 4))[cg];
        }
        const float4 yv = reinterpret_cast<const float4*>(yin + ((size_t)sp << 4))[cg];
        const float2 f0 = __half22float2(*reinterpret_cast<const __half2*>(&eaw.x));
        const float2 f1 = __half22float2(*reinterpret_cast<const __half2*>(&eaw.y));
        float m, ez;
        m = fmaxf(yv.x + f0.x, 0.f) + 1e-7f; ez = __expf(tv * m); s.x += ez; num.x += m * ez;
        m = fmaxf(yv.y + f0.y, 0.f) + 1e-7f; ez = __expf(tv * m); s.y += ez; num.y += m * ez;
        m = fmaxf(yv.z + f1.x, 0.f) + 1e-7f; ez = __expf(tv * m); s.z += ez; num.z += m * ez;
        m = fmaxf(yv.w + f1.y, 0.f) + 1e-7f; ez = __expf(tv * m); s.w += ez; num.w += m * ez;
        i = i2; has = has2;
    }
    s.x += __shfl_xor(s.x, 4); s.y += __shfl_xor(s.y, 4);
    s.z += __shfl_xor(s.z, 4); s.w += __shfl_xor(s.w, 4);
    num.x += __shfl_xor(num.x, 4); num.y += __shfl_xor(num.y, 4);
    num.z += __shfl_xor(num.z, 4); num.w += __shfl_xor(num.w, 4);
    s.x += __shfl_xor(s.x, 8); s.y += __shfl_xor(s.y, 8);
    s.z += __shfl_xor(s.z, 8); s.w += __shfl_xor(s.w, 8);
    num.x += __shfl_xor(num.x, 8); num.y += __shfl_xor(num.y, 8);
    num.z += __shfl_xor(num.z, 8); num.w += __shfl_xor(num.w, 8);
    if (es == 0) {
        float4 r;
        r.x = num.x / (s.x + 1e-16f);
        r.y = num.y / (s.y + 1e-16f);
        r.z = num.z / (s.z + 1e-16f);
        r.w = num.w / (s.w + 1e-16f);
        reinterpret_cast<float4*>(aggr + ((size_t)n << 4))[cg] = r;
    }
}

// ---------------- node pass: MLP + residual + next-norm ----------------
__global__ __launch_bounds__(256) void k_node(
    const float* __restrict__ yin, const float* __restrict__ hprev,
    const float* __restrict__ aggr,
    const float* __restrict__ w1, const float* __restrict__ b1,
    const float* __restrict__ g1, const float* __restrict__ be1,
    const float* __restrict__ w2, const float* __restrict__ b2,
    const float* __restrict__ gn, const float* __restrict__ bn,
    float* __restrict__ hout, float* __restrict__ yout, int layer)
{
    __shared__ float4 W1[128];
    __shared__ float4 W2[128];
    __shared__ float B1[32], G1[32], BE1[32], B2[16], GN[16], BN[16];
    const int tid = threadIdx.x;
    if (tid < 128) {
        W1[tid] = reinterpret_cast<const float4*>(w1)[tid];
        W2[tid] = reinterpret_cast<const float4*>(w2)[tid];
    }
    if (tid < 32) { B1[tid] = b1[tid]; G1[tid] = g1[tid]; BE1[tid] = be1[tid]; }
    if (tid < 16) { B2[tid] = b2[tid]; GN[tid] = gn[tid]; BN[tid] = bn[tid]; }
    __syncthreads();
    const int n = blockIdx.x * 256 + tid;
    if (n >= N_NODES) return;
    const size_t base = (size_t)n * HID;

    float hin[16];
    {
        const float4* yg = reinterpret_cast<const float4*>(yin + base);
        const float4* ag = reinterpret_cast<const float4*>(aggr + base);
        #pragma unroll
        for (int q = 0; q < 4; ++q) {
            float4 yv = yg[q], av = ag[q];
            hin[q * 4 + 0] = yv.x + av.x;
            hin[q * 4 + 1] = yv.y + av.y;
            hin[q * 4 + 2] = yv.z + av.z;
            hin[q * 4 + 3] = yv.w + av.w;
        }
    }
    float z[32];
    #pragma unroll
    for (int i = 0; i < 32; ++i) z[i] = B1[i];
    #pragma unroll
    for (int j = 0; j < 16; ++j) {
        const float hv = hin[j];
        #pragma unroll
        for (int q = 0; q < 8; ++q) {
            float4 w = W1[j * 8 + q];
            z[q * 4 + 0] += hv * w.x; z[q * 4 + 1] += hv * w.y;
            z[q * 4 + 2] += hv * w.z; z[q * 4 + 3] += hv * w.w;
        }
    }
    float mu = 0.f;
    #pragma unroll
    for (int i = 0; i < 32; ++i) mu += z[i];
    mu *= (1.f / 32.f);
    float var = 0.f;
    #pragma unroll
    for (int i = 0; i < 32; ++i) { float d = z[i] - mu; var += d * d; }
    var *= (1.f / 32.f);
    const float rs = rsqrtf(var + 1e-5f);

    float o[16];
    #pragma unroll
    for (int j = 0; j < 16; ++j) o[j] = B2[j];
    #pragma unroll
    for (int i = 0; i < 32; ++i) {
        const float r = fmaxf((z[i] - mu) * rs * G1[i] + BE1[i], 0.f);
        #pragma unroll
        for (int q = 0; q < 4; ++q) {
            float4 w = W2[i * 4 + q];
            o[q * 4 + 0] += r * w.x; o[q * 4 + 1] += r * w.y;
            o[q * 4 + 2] += r * w.z; o[q * 4 + 3] += r * w.w;
        }
    }
    float hn[16];
    if (layer == 0) {
        #pragma unroll
        for (int j = 0; j < 16; ++j) hn[j] = o[j];
    } else {
        const float4* hg = reinterpret_cast<const float4*>(hprev + base);
        float hr[16];
        *reinterpret_cast<float4*>(&hr[0])  = hg[0];
        *reinterpret_cast<float4*>(&hr[4])  = hg[1];
        *reinterpret_cast<float4*>(&hr[8])  = hg[2];
        *reinterpret_cast<float4*>(&hr[12]) = hg[3];
        #pragma unroll
        for (int j = 0; j < 16; ++j) hn[j] = hr[j] + o[j];
    }
    {
        float4* ho = reinterpret_cast<float4*>(hout + base);
        #pragma unroll
        for (int q = 0; q < 4; ++q)
            ho[q] = make_float4(hn[q*4+0], hn[q*4+1], hn[q*4+2], hn[q*4+3]);
    }
    float mu2 = 0.f;
    #pragma unroll
    for (int j = 0; j < 16; ++j) mu2 += hn[j];
    mu2 *= (1.f / 16.f);
    float v2 = 0.f;
    #pragma unroll
    for (int j = 0; j < 16; ++j) { float d = hn[j] - mu2; v2 += d * d; }
    v2 *= (1.f / 16.f);
    const float rs2 = rsqrtf(v2 + 1e-5f);
    float yn[16];
    #pragma unroll
    for (int j = 0; j < 16; ++j)
        yn[j] = fmaxf((hn[j] - mu2) * rs2 * GN[j] + BN[j], 0.f);
    {
        float4* yo = reinterpret_cast<float4*>(yout + base);
        #pragma unroll
        for (int q = 0; q < 4; ++q)
            yo[q] = make_float4(yn[q*4+0], yn[q*4+1], yn[q*4+2], yn[q*4+3]);
    }
}

// ---------------- v0 FALLBACK fused layer (round-4, proven) --------------
__global__ __launch_bounds__(256) void k_layer(
    const float* __restrict__ yin, const float* __restrict__ hprev,
    const int* __restrict__ rowptr, const int* __restrict__ csr,
    const int* __restrict__ srcA, const float* __restrict__ eattr,
    const float* __restrict__ ew, const float* __restrict__ ebv,
    const float* __restrict__ tArr, int layer,
    const float* __restrict__ w1, const float* __restrict__ b1,
    const float* __restrict__ g1, const float* __restrict__ be1,
    const float* __restrict__ w2, const float* __restrict__ b2,
    const float* __restrict__ gn, const float* __restrict__ bn,
    float* __restrict__ hout, float* __restrict__ yout)
{
    __shared__ float EW[256];
    __shared__ float EB[16];
    __shared__ float4 W1[128];
    __shared__ float4 W2[128];
    __shared__ float B1[32], G1[32], BE1[32], B2[16], GN[16], BN[16];
    const int tid = threadIdx.x;
    EW[tid] = ew[tid];
    if (tid < 128) {
        W1[tid] = reinterpret_cast<const float4*>(w1)[tid];
        W2[tid] = reinterpret_cast<const float4*>(w2)[tid];
    }
    if (tid < 32) { B1[tid] = b1[tid]; G1[tid] = g1[tid]; BE1[tid] = be1[tid]; }
    if (tid < 16) { EB[tid] = ebv[tid]; B2[tid] = b2[tid]; GN[tid] = gn[tid]; BN[tid] = bn[tid]; }
    __syncthreads();

    const int t = blockIdx.x * 256 + tid;
    const int n = t >> 2, sub = t & 3;
    if (n >= N_NODES) return;
    const int row0 = rowptr[n], row1 = rowptr[n + 1];
    const float tv = tArr[layer];

    float s[16], num[16];
    #pragma unroll
    for (int j = 0; j < 16; ++j) { s[j] = 0.f; num[j] = 0.f; }

    for (int i = row0 + sub; i < row1; i += 4) {
        const int eid = csr[i];
        const int sp = srcA[eid];
        float a[16], yv[16];
        {
            const float4* ag = reinterpret_cast<const float4*>(eattr + (size_t)eid * 16);
            *reinterpret_cast<float4*>(&a[0])  = ag[0];
            *reinterpret_cast<float4*>(&a[4])  = ag[1];
            *reinterpret_cast<float4*>(&a[8])  = ag[2];
            *reinterpret_cast<float4*>(&a[12]) = ag[3];
            const float4* yg = reinterpret_cast<const float4*>(yin + (size_t)sp * 16);
            *reinterpret_cast<float4*>(&yv[0])  = yg[0];
            *reinterpret_cast<float4*>(&yv[4])  = yg[1];
            *reinterpret_cast<float4*>(&yv[8])  = yg[2];
            *reinterpret_cast<float4*>(&yv[12]) = yg[3];
        }
        float acc[16];
        #pragma unroll
        for (int j = 0; j < 16; ++j) acc[j] = EB[j];
        #pragma unroll
        for (int k = 0; k < 16; ++k) {
            const float av = a[k];
            #pragma unroll
            for (int j = 0; j < 16; ++j) acc[j] += av * EW[k * 16 + j];
        }
        #pragma unroll
        for (int j = 0; j < 16; ++j) {
            float m = fmaxf(yv[j] + acc[j], 0.f) + 1e-7f;
            float ez = __expf(tv * m);
            s[j] += ez;
            num[j] += m * ez;
        }
    }
    #pragma unroll
    for (int j = 0; j < 16; ++j) {
        s[j]   += __shfl_xor(s[j], 1);   num[j] += __shfl_xor(num[j], 1);
        s[j]   += __shfl_xor(s[j], 2);   num[j] += __shfl_xor(num[j], 2);
    }
    if (sub != 0) return;

    const size_t base = (size_t)n * HID;
    float hin[16];
    {
        const float4* yg = reinterpret_cast<const float4*>(yin + base);
        float yr[16];
        *reinterpret_cast<float4*>(&yr[0])  = yg[0];
        *reinterpret_cast<float4*>(&yr[4])  = yg[1];
        *reinterpret_cast<float4*>(&yr[8])  = yg[2];
        *reinterpret_cast<float4*>(&yr[12]) = yg[3];
        #pragma unroll
        for (int j = 0; j < 16; ++j) hin[j] = yr[j] + num[j] / (s[j] + 1e-16f);
    }
    float z[32];
    #pragma unroll
    for (int i = 0; i < 32; ++i) z[i] = B1[i];
    #pragma unroll
    for (int j = 0; j < 16; ++j) {
        const float hv = hin[j];
        #pragma unroll
        for (int q = 0; q < 8; ++q) {
            float4 w = W1[j * 8 + q];
            z[q * 4 + 0] += hv * w.x; z[q * 4 + 1] += hv * w.y;
            z[q * 4 + 2] += hv * w.z; z[q * 4 + 3] += hv * w.w;
        }
    }
    float mu = 0.f;
    #pragma unroll
    for (int i = 0; i < 32; ++i) mu += z[i];
    mu *= (1.f / 32.f);
    float var = 0.f;
    #pragma unroll
    for (int i = 0; i < 32; ++i) { float d = z[i] - mu; var += d * d; }
    var *= (1.f / 32.f);
    const float rs = rsqrtf(var + 1e-5f);

    float o[16];
    #pragma unroll
    for (int j = 0; j < 16; ++j) o[j] = B2[j];
    #pragma unroll
    for (int i = 0; i < 32; ++i) {
        const float r = fmaxf((z[i] - mu) * rs * G1[i] + BE1[i], 0.f);
        #pragma unroll
        for (int q = 0; q < 4; ++q) {
            float4 w = W2[i * 4 + q];
            o[q * 4 + 0] += r * w.x; o[q * 4 + 1] += r * w.y;
            o[q * 4 + 2] += r * w.z; o[q * 4 + 3] += r * w.w;
        }
    }
    float hn[16];
    if (layer == 0) {
        #pragma unroll
        for (int j = 0; j < 16; ++j) hn[j] = o[j];
    } else {
        const float4* hg = reinterpret_cast<const float4*>(hprev + base);
        float hr[16];
        *reinterpret_cast<float4*>(&hr[0])  = hg[0];
        *reinterpret_cast<float4*>(&hr[4])  = hg[1];
        *reinterpret_cast<float4*>(&hr[8])  = hg[2];
        *reinterpret_cast<float4*>(&hr[12]) = hg[3];
        #pragma unroll
        for (int j = 0; j < 16; ++j) hn[j] = hr[j] + o[j];
    }
    {
        float4* ho = reinterpret_cast<float4*>(hout + base);
        #pragma unroll
        for (int q = 0; q < 4; ++q)
            ho[q] = make_float4(hn[q*4+0], hn[q*4+1], hn[q*4+2], hn[q*4+3]);
    }
    float mu2 = 0.f;
    #pragma unroll
    for (int j = 0; j < 16; ++j) mu2 += hn[j];
    mu2 *= (1.f / 16.f);
    float v2 = 0.f;
    #pragma unroll
    for (int j = 0; j < 16; ++j) { float d = hn[j] - mu2; v2 += d * d; }
    v2 *= (1.f / 16.f);
    const float rs2 = rsqrtf(v2 + 1e-5f);
    float yn[16];
    #pragma unroll
    for (int j = 0; j < 16; ++j)
        yn[j] = fmaxf((hn[j] - mu2) * rs2 * GN[j] + BN[j], 0.f);
    {
        float4* yo = reinterpret_cast<float4*>(yout + base);
        #pragma unroll
        for (int q = 0; q < 4; ++q)
            yo[q] = make_float4(yn[q*4+0], yn[q*4+1], yn[q*4+2], yn[q*4+3]);
    }
}

// ---------------- pooling: one block per graph, no atomics ----------------
__global__ __launch_bounds__(256) void k_pool(
    const float* __restrict__ y, const int* __restrict__ batch,
    float* __restrict__ gmax, float* __restrict__ gsum, float* __restrict__ gcnt)
{
    const int g = blockIdx.x;
    const int tid = threadIdx.x;
    int lo = 0, hi = N_NODES;
    while (lo < hi) { int mid = (lo + hi) >> 1; if (batch[mid] < g) lo = mid + 1; else hi = mid; }
    const int start = lo;
    lo = 0; hi = N_NODES;
    while (lo < hi) { int mid = (lo + hi) >> 1; if (batch[mid] < g + 1) lo = mid + 1; else hi = mid; }
    const int end = lo;

    const int ch = tid & 15, slot = tid >> 4;
    float mx = 0.f, sm = 0.f;
    for (int n = start + slot; n < end; n += 16) {
        float v = y[(size_t)n * HID + ch];
        mx = fmaxf(mx, v);
        sm += v;
    }
    __shared__ float rm[256], rsum[256];
    rm[tid] = mx; rsum[tid] = sm;
    __syncthreads();
    for (int off = 8; off >= 1; off >>= 1) {
        if (slot < off) {
            rm[tid] = fmaxf(rm[tid], rm[tid + off * 16]);
            rsum[tid] += rsum[tid + off * 16];
        }
        __syncthreads();
    }
    if (slot == 0) {
        gmax[g * HID + ch] = rm[ch];
        gsum[g * HID + ch] = rsum[ch];
        if (ch == 0) gcnt[g] = (float)(end - start);
    }
}

// ---------------- final MLP head ----------------
__global__ __launch_bounds__(128) void k_final(
    const float* __restrict__ gmax, const float* __restrict__ gsum,
    const float* __restrict__ gcnt, const float* __restrict__ action,
    const float* __restrict__ pin_w, const float* __restrict__ pin_b,
    const float* __restrict__ ph_w, const float* __restrict__ ph_b,
    const float* __restrict__ po_w, const float* __restrict__ po_b,
    float* __restrict__ out)
{
    __shared__ float mol[32];
    __shared__ float fpv[128];
    __shared__ float pol[10];
    const int b = blockIdx.x, tid = threadIdx.x;
    if (tid < 16) mol[tid] = gmax[b * 16 + tid];
    else if (tid < 32) mol[tid] = gsum[b * 16 + (tid - 16)] / gcnt[b];
    __syncthreads();
    float acc = pin_b[tid];
    #pragma unroll 4
    for (int k = 0; k < 32; ++k) acc += mol[k] * pin_w[k * 128 + tid];
    fpv[tid] = fmaxf(acc, 0.f);
    __syncthreads();
    if (tid < 10) {
        float a2 = ph_b[tid];
        for (int k = 0; k < 128; ++k) a2 += fpv[k] * ph_w[k * 10 + tid];
        #pragma unroll
        for (int k = 0; k < 6; ++k) a2 += action[b * 6 + k] * ph_w[(128 + k) * 10 + tid];
        pol[tid] = fmaxf(a2, 0.f);
    }
    __syncthreads();
    if (tid == 0) {
        float o = po_b[0];
        #pragma unroll
        for (int i = 0; i < 10; ++i) o += pol[i] * po_w[i];
        out[b] = o;
    }
}

extern "C" void kernel_launch(void* const* d_in, const int* in_sizes, int n_in,
                              void* d_out, int out_size, void* d_ws, size_t ws_size,
                              hipStream_t stream)
{
    const float* x       = (const float*)d_in[0];
    const float* eattr   = (const float*)d_in[1];
    const int*   eidx    = (const int*)d_in[2];
    const int*   batch   = (const int*)d_in[3];
    const float* action  = (const float*)d_in[4];
    const float* node_w  = (const float*)d_in[5];
    const float* node_b  = (const float*)d_in[6];
    const float* edge_w  = (const float*)d_in[7];
    const float* edge_b  = (const float*)d_in[8];
    const float* tArr    = (const float*)d_in[9];
    const float* mlp_w1  = (const float*)d_in[10];
    const float* mlp_b1  = (const float*)d_in[11];
    const float* mlp_g1  = (const float*)d_in[12];
    const float* mlp_be1 = (const float*)d_in[13];
    const float* mlp_w2  = (const float*)d_in[14];
    const float* mlp_b2  = (const float*)d_in[15];
    const float* ln_g    = (const float*)d_in[16];
    const float* ln_b    = (const float*)d_in[17];
    const float* pin_w   = (const float*)d_in[18];
    const float* pin_b   = (const float*)d_in[19];
    const float* ph_w    = (const float*)d_in[20];
    const float* ph_b    = (const float*)d_in[21];
    const float* po_w    = (const float*)d_in[22];
    const float* po_b    = (const float*)d_in[23];
    float* out = (float*)d_out;

    char* ws = (char*)d_ws;
    float* h      = (float*)ws;                                  // N*16
    float* y      = h + (size_t)N_NODES * HID;                   // N*16
    float* aggr   = y + (size_t)N_NODES * HID;                   // N*16
    int*   cnt    = (int*)(aggr + (size_t)N_NODES * HID);        // N
    int*   rowptr = cnt + N_NODES;                               // N+1
    int*   bsum   = rowptr + N_NODES + 1;                        // NSCAN_BLK
    int*   offs   = bsum + NSCAN_BLK;                            // NSCAN_BLK
    int*   csr    = offs + NSCAN_BLK + 1;                        // E (v0 / binTot+binStart)
    float* gmax   = (float*)(csr + N_EDGES);                     // 64*16
    float* gsum   = gmax + NB * HID;                             // 64*16
    float* gcnt   = gsum + NB * HID;                             // 64
    int*   srcP   = (int*)(gcnt + NB);                           // E
    __half* eaPh  = (__half*)(srcP + N_EDGES);                   // E*16 half
    __half* eaE   = eaPh + (size_t)N_EDGES * HID;                // E*16 half
    const size_t need = (size_t)((char*)(eaE + (size_t)N_EDGES * HID) - ws);
    const bool fast = (ws_size >= need);
    (void)in_sizes; (void)n_in; (void)out_size;

    // fast-path overlays (regions dead during CSR build):
    int2* partK   = (int2*)h;              // E int2 = 12.8MB (h + y)
    int* histG    = (int*)aggr;            // NPBLK*NBIN = 256KB
    int* boffsG   = histG + NPBLK * NBIN;  // 256KB (aggr = 6.4MB: fits)
    int* binTot   = csr;                   // NBIN
    int* binStart = csr + NBIN;            // NBIN+1

    const int* srcA = eidx;
    const int* dstA = eidx + N_EDGES;

    if (fast) {
        // ---- key-only binned CSR build + one-time payload permutation ----
        k_edgemlp<<<N_EDGES / 256, 256, 0, stream>>>(eattr, edge_w, edge_b, eaE);
        k_hist1<<<NPBLK, 256, 0, stream>>>(dstA, histG);
        k_scanblk<<<NBIN, NPBLK, 0, stream>>>(histG, boffsG, binTot);
        k_scanbin<<<1, NBIN, 0, stream>>>(binTot, binStart);
        k_partl<<<NPBLK, 256, 0, stream>>>(dstA, srcA, boffsG, binStart, partK);
        k_finishl<<<NBIN, 512, 0, stream>>>(partK, eaE, binStart, rowptr,
            srcP, eaPh);
        // ---- layers ----
        k_embed<<<N_NODES / 16, 256, 0, stream>>>(x, node_w, node_b, y);
        const int gridA = (16 * N_NODES + 255) / 256;
        const int gridN = (N_NODES + 255) / 256;
        for (int l = 0; l < NL; ++l) {
            const int nidx = (l < 3) ? (l + 1) : 0;
            k_aggr<<<gridA, 256, 0, stream>>>(y, rowptr, srcP, eaPh, tArr, l, aggr);
            k_node<<<gridN, 256, 0, stream>>>(y, h, aggr,
                mlp_w1 + l * 512, mlp_b1 + l * 32, mlp_g1 + l * 32, mlp_be1 + l * 32,
                mlp_w2 + l * 512, mlp_b2 + l * 16, ln_g + nidx * 16, ln_b + nidx * 16,
                h, y, l);
        }
        k_pool<<<NB, 256, 0, stream>>>(y, batch, gmax, gsum, gcnt);
    } else {
        // ---- v0 fallback (round-4 proven): atomic CSR + fused k_layer ----
        hipMemsetAsync(cnt, 0, (size_t)N_NODES * sizeof(int), stream);
        k_count<<<(N_EDGES + 255) / 256, 256, 0, stream>>>(dstA, cnt);
        k_scan1<<<NSCAN_BLK, 256, 0, stream>>>(cnt, rowptr, bsum);
        k_scan2<<<1, 512, 0, stream>>>(bsum, offs, rowptr);
        k_scan3<<<NSCAN_BLK, 256, 0, stream>>>(rowptr, offs, cnt);
        k_fill<<<(N_EDGES + 255) / 256, 256, 0, stream>>>(dstA, rowptr, cnt, csr);
        float* yA = y;
        float* yB = aggr;
        k_embed<<<N_NODES / 16, 256, 0, stream>>>(x, node_w, node_b, yA);
        const int grid = (4 * N_NODES + 255) / 256;
        for (int l = 0; l < NL; ++l) {
            const float* yin = (l & 1) ? yB : yA;
            float* yout      = (l & 1) ? yA : yB;
            const int nidx = (l < 3) ? (l + 1) : 0;
            k_layer<<<grid, 256, 0, stream>>>(
                yin, h, rowptr, csr, srcA, eattr, edge_w, edge_b, tArr, l,
                mlp_w1 + l * 512, mlp_b1 + l * 32, mlp_g1 + l * 32, mlp_be1 + l * 32,
                mlp_w2 + l * 512, mlp_b2 + l * 16, ln_g + nidx * 16, ln_b + nidx * 16,
                h, yout);
        }
        k_pool<<<NB, 256, 0, stream>>>(yA, batch, gmax, gsum, gcnt);
    }
    k_final<<<NB, 128, 0, stream>>>(gmax, gsum, gcnt, action,
        pin_w, pin_b, ph_w, ph_b, po_w, po_b, out);
}

// Round 13
// 347.198 us; speedup vs baseline: 1.9762x; 1.0884x over previous
//
#include <hip/hip_runtime.h>
#include <hip/hip_fp16.h>

#define N_NODES 100000
#define N_EDGES 1600000
#define NB 64
#define F_INn 64
#define HID 16
#define NL 4
#define NSCAN_BLK 391   // ceil(N_NODES/256) (fallback path)
#define NBIN 256
#define BINW 391        // ceil(100000/256); 391*256 = 100096 >= N
#define NPBLK 256

__device__ __forceinline__ unsigned pack2h(float a, float b) {
    __half2 h = __floats2half2_rn(a, b);
    return *reinterpret_cast<unsigned*>(&h);
}

__device__ __forceinline__ void blk_range(int blk, int& e0, int& e1) {
    e0 = (int)(((long long)blk * N_EDGES) / NPBLK);
    e1 = (int)(((long long)(blk + 1) * N_EDGES) / NPBLK);
}

// ---------------- node embedding: y0 = x @ node_w + node_b ----------------
__global__ __launch_bounds__(256) void k_embed(
    const float* __restrict__ x, const float* __restrict__ nw,
    const float* __restrict__ nb, float* __restrict__ yout)
{
    __shared__ float xs[16 * 64];
    __shared__ float Wn[64 * 16];
    __shared__ float Bn[16];
    const int tid = threadIdx.x;
    for (int i = tid; i < 1024; i += 256) Wn[i] = nw[i];
    if (tid < 16) Bn[tid] = nb[tid];
    const int n0 = blockIdx.x * 16;
    reinterpret_cast<float4*>(xs)[tid] =
        reinterpret_cast<const float4*>(x + (size_t)n0 * F_INn)[tid];
    __syncthreads();
    const int nl = tid >> 4, j = tid & 15;
    float acc = Bn[j];
    #pragma unroll 8
    for (int k = 0; k < 64; ++k) acc += xs[nl * 64 + k] * Wn[k * 16 + j];
    yout[(size_t)(n0 + nl) * HID + j] = acc;
}

// ================= binned CSR build: keys only (8B) =======================
__global__ __launch_bounds__(256) void k_hist1(
    const int* __restrict__ dstA, int* __restrict__ histG)
{
    __shared__ int h[NBIN];
    const int tid = threadIdx.x, blk = blockIdx.x;
    for (int t = tid; t < NBIN; t += 256) h[t] = 0;
    __syncthreads();
    int e0, e1; blk_range(blk, e0, e1);
    for (int e = e0 + tid; e < e1; e += 256)
        atomicAdd(&h[dstA[e] / BINW], 1);
    __syncthreads();
    for (int t = tid; t < NBIN; t += 256) histG[blk * NBIN + t] = h[t];
}

__global__ __launch_bounds__(NPBLK) void k_scanblk(
    const int* __restrict__ histG, int* __restrict__ boffsG,
    int* __restrict__ binTot)
{
    __shared__ int sc[NPBLK];
    const int tid = threadIdx.x, bin = blockIdx.x;
    const int v = histG[tid * NBIN + bin];
    sc[tid] = v;
    __syncthreads();
    for (int off = 1; off < NPBLK; off <<= 1) {
        int t = (tid >= off) ? sc[tid - off] : 0;
        __syncthreads();
        sc[tid] += t;
        __syncthreads();
    }
    boffsG[tid * NBIN + bin] = sc[tid] - v;
    if (tid == NPBLK - 1) binTot[bin] = sc[tid];
}

__global__ __launch_bounds__(NBIN) void k_scanbin(
    const int* __restrict__ binTot, int* __restrict__ binStart)
{
    __shared__ int sc[NBIN];
    const int tid = threadIdx.x;
    const int v = binTot[tid];
    sc[tid] = v;
    __syncthreads();
    for (int off = 1; off < NBIN; off <<= 1) {
        int t = (tid >= off) ? sc[tid - off] : 0;
        __syncthreads();
        sc[tid] += t;
        __syncthreads();
    }
    binStart[tid] = sc[tid] - v;
    if (tid == NBIN - 1) binStart[NBIN] = sc[tid];
}

// partition keys: partK[p] = {src, (dloc<<21)|e}  (dloc<512, e<2^21)
__global__ __launch_bounds__(256) void k_partl(
    const int* __restrict__ dstA, const int* __restrict__ srcA,
    const int* __restrict__ boffsG, const int* __restrict__ binStart,
    int2* __restrict__ partK)
{
    __shared__ int cur[NBIN];
    const int tid = threadIdx.x, blk = blockIdx.x;
    for (int t = tid; t < NBIN; t += 256)
        cur[t] = binStart[t] + boffsG[blk * NBIN + t];
    __syncthreads();
    int e0, e1; blk_range(blk, e0, e1);
    for (int e = e0 + tid; e < e1; e += 256) {
        const int d = dstA[e];
        const int bin = d / BINW;
        const int dloc = d - bin * BINW;
        const int p = atomicAdd(&cur[bin], 1);
        partK[p] = make_int2(srcA[e], (dloc << 21) | e);
    }
}

// fused per-bin: count + scan -> rowptr, then place srcP/csrE (4B each)
__global__ __launch_bounds__(512) void k_finishl(
    const int2* __restrict__ partK, const int* __restrict__ binStart,
    int* __restrict__ rowptr, int* __restrict__ srcP, int* __restrict__ csrE)
{
    __shared__ int h[BINW];
    __shared__ int sc[512];
    __shared__ int cur[BINW];
    const int tid = threadIdx.x, bin = blockIdx.x;
    const int base = bin * BINW;
    for (int t = tid; t < BINW; t += 512) h[t] = 0;
    __syncthreads();
    const int i0 = binStart[bin], i1 = binStart[bin + 1];
    for (int i = i0 + tid; i < i1; i += 512)
        atomicAdd(&h[partK[i].y >> 21], 1);
    __syncthreads();
    const int v = (tid < BINW) ? h[tid] : 0;
    sc[tid] = v;
    __syncthreads();
    for (int off = 1; off < 512; off <<= 1) {
        int t = (tid >= off) ? sc[tid - off] : 0;
        __syncthreads();
        sc[tid] += t;
        __syncthreads();
    }
    if (tid < BINW) {
        const int r = i0 + sc[tid] - v;
        const int idx = base + tid;
        if (idx < N_NODES) rowptr[idx] = r;
        cur[tid] = r;
    }
    if (bin == NBIN - 1 && tid == 0) rowptr[N_NODES] = N_EDGES;
    __syncthreads();
    for (int i = i0 + tid; i < i1; i += 512) {
        const int2 w = partK[i];
        const int dloc = w.y >> 21;
        const int p = atomicAdd(&cur[dloc], 1);
        srcP[p] = w.x;
        csrE[p] = w.y & 0x1FFFFF;
    }
}

// edge-MLP at CSR position: coalesced csrE read, random eattr gather,
// SEQUENTIAL fp16 payload write. Replaces k_edgemlp + finishl-payload.
__global__ __launch_bounds__(256) void k_permea(
    const int* __restrict__ csrE, const float* __restrict__ eattr,
    const float* __restrict__ ew, const float* __restrict__ ebv,
    __half* __restrict__ eaPh)
{
    __shared__ float EW[256];
    __shared__ float EB[16];
    const int tid = threadIdx.x;
    EW[tid] = ew[tid];
    if (tid < 16) EB[tid] = ebv[tid];
    __syncthreads();
    const int p = blockIdx.x * 256 + tid;   // E divisible by 256
    const int e = csrE[p];
    float acc[16];
    #pragma unroll
    for (int j = 0; j < 16; ++j) acc[j] = EB[j];
    const float4* ag = reinterpret_cast<const float4*>(eattr + ((size_t)e << 4));
    #pragma unroll
    for (int q = 0; q < 4; ++q) {
        const float4 av = ag[q];
        #pragma unroll
        for (int j = 0; j < 16; ++j) {
            acc[j] += av.x * EW[(q * 4 + 0) * 16 + j];
            acc[j] += av.y * EW[(q * 4 + 1) * 16 + j];
            acc[j] += av.z * EW[(q * 4 + 2) * 16 + j];
            acc[j] += av.w * EW[(q * 4 + 3) * 16 + j];
        }
    }
    uint4 lo, hi;
    lo.x = pack2h(acc[0], acc[1]);   lo.y = pack2h(acc[2], acc[3]);
    lo.z = pack2h(acc[4], acc[5]);   lo.w = pack2h(acc[6], acc[7]);
    hi.x = pack2h(acc[8], acc[9]);   hi.y = pack2h(acc[10], acc[11]);
    hi.z = pack2h(acc[12], acc[13]); hi.w = pack2h(acc[14], acc[15]);
    uint4* eo = reinterpret_cast<uint4*>(eaPh) + ((size_t)p << 1);
    eo[0] = lo;
    eo[1] = hi;
}

// ---------------- v0 fallback CSR build pieces ----------------
__global__ __launch_bounds__(256) void k_count(
    const int* __restrict__ dstA, int* __restrict__ cnt)
{
    const int e = blockIdx.x * 256 + threadIdx.x;
    if (e < N_EDGES) atomicAdd(cnt + dstA[e], 1);
}

__global__ __launch_bounds__(256) void k_scan1(
    const int* __restrict__ cnt, int* __restrict__ rowptr, int* __restrict__ bsum)
{
    __shared__ int sc[256];
    const int tid = threadIdx.x;
    const int i = blockIdx.x * 256 + tid;
    const int v = (i < N_NODES) ? cnt[i] : 0;
    sc[tid] = v;
    __syncthreads();
    for (int off = 1; off < 256; off <<= 1) {
        int t = (tid >= off) ? sc[tid - off] : 0;
        __syncthreads();
        sc[tid] += t;
        __syncthreads();
    }
    if (i < N_NODES) rowptr[i] = sc[tid] - v;
    if (tid == 255) bsum[blockIdx.x] = sc[tid];
}

__global__ __launch_bounds__(512) void k_scan2(
    const int* __restrict__ bsum, int* __restrict__ offs, int* __restrict__ rowptr)
{
    __shared__ int sc[512];
    const int tid = threadIdx.x;
    const int v = (tid < NSCAN_BLK) ? bsum[tid] : 0;
    sc[tid] = v;
    __syncthreads();
    for (int off = 1; off < 512; off <<= 1) {
        int t = (tid >= off) ? sc[tid - off] : 0;
        __syncthreads();
        sc[tid] += t;
        __syncthreads();
    }
    if (tid < NSCAN_BLK) offs[tid] = sc[tid] - v;
    if (tid == NSCAN_BLK - 1) rowptr[N_NODES] = sc[tid];
}

__global__ __launch_bounds__(256) void k_scan3(
    int* __restrict__ rowptr, const int* __restrict__ offs, int* __restrict__ cnt)
{
    const int i = blockIdx.x * 256 + threadIdx.x;
    if (i < N_NODES) {
        rowptr[i] += offs[i >> 8];
        cnt[i] = 0;
    }
}

__global__ __launch_bounds__(256) void k_fill(
    const int* __restrict__ dstA, const int* __restrict__ rowptr,
    int* __restrict__ cnt, int* __restrict__ csr)
{
    const int e = blockIdx.x * 256 + threadIdx.x;
    if (e >= N_EDGES) return;
    const int d = dstA[e];
    const int pos = atomicAdd(cnt + d, 1);
    csr[rowptr[d] + pos] = e;
}

// ---------------- per-layer aggregation: 16 lanes/node, fp16 ea stream ---
__global__ __launch_bounds__(256, 8) void k_aggr(
    const float* __restrict__ yin, const int* __restrict__ rowptr,
    const int* __restrict__ srcP, const __half* __restrict__ eaPh,
    const float* __restrict__ tArr, int layer, float* __restrict__ aggr)
{
    const int t = blockIdx.x * 256 + threadIdx.x;
    const int n = t >> 4;
    if (n >= N_NODES) return;
    const int sub = threadIdx.x & 15;
    const int es = sub >> 2, cg = sub & 3;
    const int row0 = rowptr[n], row1 = rowptr[n + 1];
    const float tv = tArr[layer];

    float4 s = make_float4(0.f, 0.f, 0.f, 0.f);
    float4 num = make_float4(0.f, 0.f, 0.f, 0.f);

    int i = row0 + es;
    bool has = (i < row1);
    int spn = 0;
    uint2 ean = make_uint2(0u, 0u);
    if (has) {
        spn = srcP[i];
        ean = reinterpret_cast<const uint2*>(eaPh + ((size_t)i << 4))[cg];
    }
    while (has) {
        const int sp = spn;
        const uint2 eaw = ean;
        const int i2 = i + 4;
        const bool has2 = (i2 < row1);
        if (has2) {
            spn = srcP[i2];
            ean = reinterpret_cast<const uint2*>(eaPh + ((size_t)i2 << 4))[cg];
        }
        const float4 yv = reinterpret_cast<const float4*>(yin + ((size_t)sp << 4))[cg];
        const float2 f0 = __half22float2(*reinterpret_cast<const __half2*>(&eaw.x));
        const float2 f1 = __half22float2(*reinterpret_cast<const __half2*>(&eaw.y));
        float m, ez;
        m = fmaxf(yv.x + f0.x, 0.f) + 1e-7f; ez = __expf(tv * m); s.x += ez; num.x += m * ez;
        m = fmaxf(yv.y + f0.y, 0.f) + 1e-7f; ez = __expf(tv * m); s.y += ez; num.y += m * ez;
        m = fmaxf(yv.z + f1.x, 0.f) + 1e-7f; ez = __expf(tv * m); s.z += ez; num.z += m * ez;
        m = fmaxf(yv.w + f1.y, 0.f) + 1e-7f; ez = __expf(tv * m); s.w += ez; num.w += m * ez;
        i = i2; has = has2;
    }
    s.x += __shfl_xor(s.x, 4); s.y += __shfl_xor(s.y, 4);
    s.z += __shfl_xor(s.z, 4); s.w += __shfl_xor(s.w, 4);
    num.x += __shfl_xor(num.x, 4); num.y += __shfl_xor(num.y, 4);
    num.z += __shfl_xor(num.z, 4); num.w += __shfl_xor(num.w, 4);
    s.x += __shfl_xor(s.x, 8); s.y += __shfl_xor(s.y, 8);
    s.z += __shfl_xor(s.z, 8); s.w += __shfl_xor(s.w, 8);
    num.x += __shfl_xor(num.x, 8); num.y += __shfl_xor(num.y, 8);
    num.z += __shfl_xor(num.z, 8); num.w += __shfl_xor(num.w, 8);
    if (es == 0) {
        float4 r;
        r.x = num.x / (s.x + 1e-16f);
        r.y = num.y / (s.y + 1e-16f);
        r.z = num.z / (s.z + 1e-16f);
        r.w = num.w / (s.w + 1e-16f);
        reinterpret_cast<float4*>(aggr + ((size_t)n << 4))[cg] = r;
    }
}

// ---------------- node pass: MLP + residual + next-norm ----------------
__global__ __launch_bounds__(256) void k_node(
    const float* __restrict__ yin, const float* __restrict__ hprev,
    const float* __restrict__ aggr,
    const float* __restrict__ w1, const float* __restrict__ b1,
    const float* __restrict__ g1, const float* __restrict__ be1,
    const float* __restrict__ w2, const float* __restrict__ b2,
    const float* __restrict__ gn, const float* __restrict__ bn,
    float* __restrict__ hout, float* __restrict__ yout, int layer)
{
    __shared__ float4 W1[128];
    __shared__ float4 W2[128];
    __shared__ float B1[32], G1[32], BE1[32], B2[16], GN[16], BN[16];
    const int tid = threadIdx.x;
    if (tid < 128) {
        W1[tid] = reinterpret_cast<const float4*>(w1)[tid];
        W2[tid] = reinterpret_cast<const float4*>(w2)[tid];
    }
    if (tid < 32) { B1[tid] = b1[tid]; G1[tid] = g1[tid]; BE1[tid] = be1[tid]; }
    if (tid < 16) { B2[tid] = b2[tid]; GN[tid] = gn[tid]; BN[tid] = bn[tid]; }
    __syncthreads();
    const int n = blockIdx.x * 256 + tid;
    if (n >= N_NODES) return;
    const size_t base = (size_t)n * HID;

    float hin[16];
    {
        const float4* yg = reinterpret_cast<const float4*>(yin + base);
        const float4* ag = reinterpret_cast<const float4*>(aggr + base);
        #pragma unroll
        for (int q = 0; q < 4; ++q) {
            float4 yv = yg[q], av = ag[q];
            hin[q * 4 + 0] = yv.x + av.x;
            hin[q * 4 + 1] = yv.y + av.y;
            hin[q * 4 + 2] = yv.z + av.z;
            hin[q * 4 + 3] = yv.w + av.w;
        }
    }
    float z[32];
    #pragma unroll
    for (int i = 0; i < 32; ++i) z[i] = B1[i];
    #pragma unroll
    for (int j = 0; j < 16; ++j) {
        const float hv = hin[j];
        #pragma unroll
        for (int q = 0; q < 8; ++q) {
            float4 w = W1[j * 8 + q];
            z[q * 4 + 0] += hv * w.x; z[q * 4 + 1] += hv * w.y;
            z[q * 4 + 2] += hv * w.z; z[q * 4 + 3] += hv * w.w;
        }
    }
    float mu = 0.f;
    #pragma unroll
    for (int i = 0; i < 32; ++i) mu += z[i];
    mu *= (1.f / 32.f);
    float var = 0.f;
    #pragma unroll
    for (int i = 0; i < 32; ++i) { float d = z[i] - mu; var += d * d; }
    var *= (1.f / 32.f);
    const float rs = rsqrtf(var + 1e-5f);

    float o[16];
    #pragma unroll
    for (int j = 0; j < 16; ++j) o[j] = B2[j];
    #pragma unroll
    for (int i = 0; i < 32; ++i) {
        const float r = fmaxf((z[i] - mu) * rs * G1[i] + BE1[i], 0.f);
        #pragma unroll
        for (int q = 0; q < 4; ++q) {
            float4 w = W2[i * 4 + q];
            o[q * 4 + 0] += r * w.x; o[q * 4 + 1] += r * w.y;
            o[q * 4 + 2] += r * w.z; o[q * 4 + 3] += r * w.w;
        }
    }
    float hn[16];
    if (layer == 0) {
        #pragma unroll
        for (int j = 0; j < 16; ++j) hn[j] = o[j];
    } else {
        const float4* hg = reinterpret_cast<const float4*>(hprev + base);
        float hr[16];
        *reinterpret_cast<float4*>(&hr[0])  = hg[0];
        *reinterpret_cast<float4*>(&hr[4])  = hg[1];
        *reinterpret_cast<float4*>(&hr[8])  = hg[2];
        *reinterpret_cast<float4*>(&hr[12]) = hg[3];
        #pragma unroll
        for (int j = 0; j < 16; ++j) hn[j] = hr[j] + o[j];
    }
    {
        float4* ho = reinterpret_cast<float4*>(hout + base);
        #pragma unroll
        for (int q = 0; q < 4; ++q)
            ho[q] = make_float4(hn[q*4+0], hn[q*4+1], hn[q*4+2], hn[q*4+3]);
    }
    float mu2 = 0.f;
    #pragma unroll
    for (int j = 0; j < 16; ++j) mu2 += hn[j];
    mu2 *= (1.f / 16.f);
    float v2 = 0.f;
    #pragma unroll
    for (int j = 0; j < 16; ++j) { float d = hn[j] - mu2; v2 += d * d; }
    v2 *= (1.f / 16.f);
    const float rs2 = rsqrtf(v2 + 1e-5f);
    float yn[16];
    #pragma unroll
    for (int j = 0; j < 16; ++j)
        yn[j] = fmaxf((hn[j] - mu2) * rs2 * GN[j] + BN[j], 0.f);
    {
        float4* yo = reinterpret_cast<float4*>(yout + base);
        #pragma unroll
        for (int q = 0; q < 4; ++q)
            yo[q] = make_float4(yn[q*4+0], yn[q*4+1], yn[q*4+2], yn[q*4+3]);
    }
}

// ---------------- v0 FALLBACK fused layer (round-4, proven) --------------
__global__ __launch_bounds__(256) void k_layer(
    const float* __restrict__ yin, const float* __restrict__ hprev,
    const int* __restrict__ rowptr, const int* __restrict__ csr,
    const int* __restrict__ srcA, const float* __restrict__ eattr,
    const float* __restrict__ ew, const float* __restrict__ ebv,
    const float* __restrict__ tArr, int layer,
    const float* __restrict__ w1, const float* __restrict__ b1,
    const float* __restrict__ g1, const float* __restrict__ be1,
    const float* __restrict__ w2, const float* __restrict__ b2,
    const float* __restrict__ gn, const float* __restrict__ bn,
    float* __restrict__ hout, float* __restrict__ yout)
{
    __shared__ float EW[256];
    __shared__ float EB[16];
    __shared__ float4 W1[128];
    __shared__ float4 W2[128];
    __shared__ float B1[32], G1[32], BE1[32], B2[16], GN[16], BN[16];
    const int tid = threadIdx.x;
    EW[tid] = ew[tid];
    if (tid < 128) {
        W1[tid] = reinterpret_cast<const float4*>(w1)[tid];
        W2[tid] = reinterpret_cast<const float4*>(w2)[tid];
    }
    if (tid < 32) { B1[tid] = b1[tid]; G1[tid] = g1[tid]; BE1[tid] = be1[tid]; }
    if (tid < 16) { EB[tid] = ebv[tid]; B2[tid] = b2[tid]; GN[tid] = gn[tid]; BN[tid] = bn[tid]; }
    __syncthreads();

    const int t = blockIdx.x * 256 + tid;
    const int n = t >> 2, sub = t & 3;
    if (n >= N_NODES) return;
    const int row0 = rowptr[n], row1 = rowptr[n + 1];
    const float tv = tArr[layer];

    float s[16], num[16];
    #pragma unroll
    for (int j = 0; j < 16; ++j) { s[j] = 0.f; num[j] = 0.f; }

    for (int i = row0 + sub; i < row1; i += 4) {
        const int eid = csr[i];
        const int sp = srcA[eid];
        float a[16], yv[16];
        {
            const float4* ag = reinterpret_cast<const float4*>(eattr + (size_t)eid * 16);
            *reinterpret_cast<float4*>(&a[0])  = ag[0];
            *reinterpret_cast<float4*>(&a[4])  = ag[1];
            *reinterpret_cast<float4*>(&a[8])  = ag[2];
            *reinterpret_cast<float4*>(&a[12]) = ag[3];
            const float4* yg = reinterpret_cast<const float4*>(yin + (size_t)sp * 16);
            *reinterpret_cast<float4*>(&yv[0])  = yg[0];
            *reinterpret_cast<float4*>(&yv[4])  = yg[1];
            *reinterpret_cast<float4*>(&yv[8])  = yg[2];
            *reinterpret_cast<float4*>(&yv[12]) = yg[3];
        }
        float acc[16];
        #pragma unroll
        for (int j = 0; j < 16; ++j) acc[j] = EB[j];
        #pragma unroll
        for (int k = 0; k < 16; ++k) {
            const float av = a[k];
            #pragma unroll
            for (int j = 0; j < 16; ++j) acc[j] += av * EW[k * 16 + j];
        }
        #pragma unroll
        for (int j = 0; j < 16; ++j) {
            float m = fmaxf(yv[j] + acc[j], 0.f) + 1e-7f;
            float ez = __expf(tv * m);
            s[j] += ez;
            num[j] += m * ez;
        }
    }
    #pragma unroll
    for (int j = 0; j < 16; ++j) {
        s[j]   += __shfl_xor(s[j], 1);   num[j] += __shfl_xor(num[j], 1);
        s[j]   += __shfl_xor(s[j], 2);   num[j] += __shfl_xor(num[j], 2);
    }
    if (sub != 0) return;

    const size_t base = (size_t)n * HID;
    float hin[16];
    {
        const float4* yg = reinterpret_cast<const float4*>(yin + base);
        float yr[16];
        *reinterpret_cast<float4*>(&yr[0])  = yg[0];
        *reinterpret_cast<float4*>(&yr[4])  = yg[1];
        *reinterpret_cast<float4*>(&yr[8])  = yg[2];
        *reinterpret_cast<float4*>(&yr[12]) = yg[3];
        #pragma unroll
        for (int j = 0; j < 16; ++j) hin[j] = yr[j] + num[j] / (s[j] + 1e-16f);
    }
    float z[32];
    #pragma unroll
    for (int i = 0; i < 32; ++i) z[i] = B1[i];
    #pragma unroll
    for (int j = 0; j < 16; ++j) {
        const float hv = hin[j];
        #pragma unroll
        for (int q = 0; q < 8; ++q) {
            float4 w = W1[j * 8 + q];
            z[q * 4 + 0] += hv * w.x; z[q * 4 + 1] += hv * w.y;
            z[q * 4 + 2] += hv * w.z; z[q * 4 + 3] += hv * w.w;
        }
    }
    float mu = 0.f;
    #pragma unroll
    for (int i = 0; i < 32; ++i) mu += z[i];
    mu *= (1.f / 32.f);
    float var = 0.f;
    #pragma unroll
    for (int i = 0; i < 32; ++i) { float d = z[i] - mu; var += d * d; }
    var *= (1.f / 32.f);
    const float rs = rsqrtf(var + 1e-5f);

    float o[16];
    #pragma unroll
    for (int j = 0; j < 16; ++j) o[j] = B2[j];
    #pragma unroll
    for (int i = 0; i < 32; ++i) {
        const float r = fmaxf((z[i] - mu) * rs * G1[i] + BE1[i], 0.f);
        #pragma unroll
        for (int q = 0; q < 4; ++q) {
            float4 w = W2[i * 4 + q];
            o[q * 4 + 0] += r * w.x; o[q * 4 + 1] += r * w.y;
            o[q * 4 + 2] += r * w.z; o[q * 4 + 3] += r * w.w;
        }
    }
    float hn[16];
    if (layer == 0) {
        #pragma unroll
        for (int j = 0; j < 16; ++j) hn[j] = o[j];
    } else {
        const float4* hg = reinterpret_cast<const float4*>(hprev + base);
        float hr[16];
        *reinterpret_cast<float4*>(&hr[0])  = hg[0];
        *reinterpret_cast<float4*>(&hr[4])  = hg[1];
        *reinterpret_cast<float4*>(&hr[8])  = hg[2];
        *reinterpret_cast<float4*>(&hr[12]) = hg[3];
        #pragma unroll
        for (int j = 0; j < 16; ++j) hn[j] = hr[j] + o[j];
    }
    {
        float4* ho = reinterpret_cast<float4*>(hout + base);
        #pragma unroll
        for (int q = 0; q < 4; ++q)
            ho[q] = make_float4(hn[q*4+0], hn[q*4+1], hn[q*4+2], hn[q*4+3]);
    }
    float mu2 = 0.f;
    #pragma unroll
    for (int j = 0; j < 16; ++j) mu2 += hn[j];
    mu2 *= (1.f / 16.f);
    float v2 = 0.f;
    #pragma unroll
    for (int j = 0; j < 16; ++j) { float d = hn[j] - mu2; v2 += d * d; }
    v2 *= (1.f / 16.f);
    const float rs2 = rsqrtf(v2 + 1e-5f);
    float yn[16];
    #pragma unroll
    for (int j = 0; j < 16; ++j)
        yn[j] = fmaxf((hn[j] - mu2) * rs2 * GN[j] + BN[j], 0.f);
    {
        float4* yo = reinterpret_cast<float4*>(yout + base);
        #pragma unroll
        for (int q = 0; q < 4; ++q)
            yo[q] = make_float4(yn[q*4+0], yn[q*4+1], yn[q*4+2], yn[q*4+3]);
    }
}

// ---------------- pooling: one block per graph, no atomics ----------------
__global__ __launch_bounds__(256) void k_pool(
    const float* __restrict__ y, const int* __restrict__ batch,
    float* __restrict__ gmax, float* __restrict__ gsum, float* __restrict__ gcnt)
{
    const int g = blockIdx.x;
    const int tid = threadIdx.x;
    int lo = 0, hi = N_NODES;
    while (lo < hi) { int mid = (lo + hi) >> 1; if (batch[mid] < g) lo = mid + 1; else hi = mid; }
    const int start = lo;
    lo = 0; hi = N_NODES;
    while (lo < hi) { int mid = (lo + hi) >> 1; if (batch[mid] < g + 1) lo = mid + 1; else hi = mid; }
    const int end = lo;

    const int ch = tid & 15, slot = tid >> 4;
    float mx = 0.f, sm = 0.f;
    for (int n = start + slot; n < end; n += 16) {
        float v = y[(size_t)n * HID + ch];
        mx = fmaxf(mx, v);
        sm += v;
    }
    __shared__ float rm[256], rsum[256];
    rm[tid] = mx; rsum[tid] = sm;
    __syncthreads();
    for (int off = 8; off >= 1; off >>= 1) {
        if (slot < off) {
            rm[tid] = fmaxf(rm[tid], rm[tid + off * 16]);
            rsum[tid] += rsum[tid + off * 16];
        }
        __syncthreads();
    }
    if (slot == 0) {
        gmax[g * HID + ch] = rm[ch];
        gsum[g * HID + ch] = rsum[ch];
        if (ch == 0) gcnt[g] = (float)(end - start);
    }
}

// ---------------- final MLP head ----------------
__global__ __launch_bounds__(128) void k_final(
    const float* __restrict__ gmax, const float* __restrict__ gsum,
    const float* __restrict__ gcnt, const float* __restrict__ action,
    const float* __restrict__ pin_w, const float* __restrict__ pin_b,
    const float* __restrict__ ph_w, const float* __restrict__ ph_b,
    const float* __restrict__ po_w, const float* __restrict__ po_b,
    float* __restrict__ out)
{
    __shared__ float mol[32];
    __shared__ float fpv[128];
    __shared__ float pol[10];
    const int b = blockIdx.x, tid = threadIdx.x;
    if (tid < 16) mol[tid] = gmax[b * 16 + tid];
    else if (tid < 32) mol[tid] = gsum[b * 16 + (tid - 16)] / gcnt[b];
    __syncthreads();
    float acc = pin_b[tid];
    #pragma unroll 4
    for (int k = 0; k < 32; ++k) acc += mol[k] * pin_w[k * 128 + tid];
    fpv[tid] = fmaxf(acc, 0.f);
    __syncthreads();
    if (tid < 10) {
        float a2 = ph_b[tid];
        for (int k = 0; k < 128; ++k) a2 += fpv[k] * ph_w[k * 10 + tid];
        #pragma unroll
        for (int k = 0; k < 6; ++k) a2 += action[b * 6 + k] * ph_w[(128 + k) * 10 + tid];
        pol[tid] = fmaxf(a2, 0.f);
    }
    __syncthreads();
    if (tid == 0) {
        float o = po_b[0];
        #pragma unroll
        for (int i = 0; i < 10; ++i) o += pol[i] * po_w[i];
        out[b] = o;
    }
}

extern "C" void kernel_launch(void* const* d_in, const int* in_sizes, int n_in,
                              void* d_out, int out_size, void* d_ws, size_t ws_size,
                              hipStream_t stream)
{
    const float* x       = (const float*)d_in[0];
    const float* eattr   = (const float*)d_in[1];
    const int*   eidx    = (const int*)d_in[2];
    const int*   batch   = (const int*)d_in[3];
    const float* action  = (const float*)d_in[4];
    const float* node_w  = (const float*)d_in[5];
    const float* node_b  = (const float*)d_in[6];
    const float* edge_w  = (const float*)d_in[7];
    const float* edge_b  = (const float*)d_in[8];
    const float* tArr    = (const float*)d_in[9];
    const float* mlp_w1  = (const float*)d_in[10];
    const float* mlp_b1  = (const float*)d_in[11];
    const float* mlp_g1  = (const float*)d_in[12];
    const float* mlp_be1 = (const float*)d_in[13];
    const float* mlp_w2  = (const float*)d_in[14];
    const float* mlp_b2  = (const float*)d_in[15];
    const float* ln_g    = (const float*)d_in[16];
    const float* ln_b    = (const float*)d_in[17];
    const float* pin_w   = (const float*)d_in[18];
    const float* pin_b   = (const float*)d_in[19];
    const float* ph_w    = (const float*)d_in[20];
    const float* ph_b    = (const float*)d_in[21];
    const float* po_w    = (const float*)d_in[22];
    const float* po_b    = (const float*)d_in[23];
    float* out = (float*)d_out;

    char* ws = (char*)d_ws;
    float* h      = (float*)ws;                                  // N*16
    float* y      = h + (size_t)N_NODES * HID;                   // N*16
    float* aggr   = y + (size_t)N_NODES * HID;                   // N*16
    int*   cnt    = (int*)(aggr + (size_t)N_NODES * HID);        // N
    int*   rowptr = cnt + N_NODES;                               // N+1
    int*   bsum   = rowptr + N_NODES + 1;                        // NSCAN_BLK
    int*   offs   = bsum + NSCAN_BLK;                            // NSCAN_BLK
    int*   csr    = offs + NSCAN_BLK + 1;                        // E (v0 / binTot+binStart)
    float* gmax   = (float*)(csr + N_EDGES);                     // 64*16
    float* gsum   = gmax + NB * HID;                             // 64*16
    float* gcnt   = gsum + NB * HID;                             // 64
    int*   srcP   = (int*)(gcnt + NB);                           // E
    int*   csrE   = srcP + N_EDGES;                              // E
    __half* eaPh  = (__half*)(csrE + N_EDGES);                   // E*16 half
    const size_t need = (size_t)((char*)(eaPh + (size_t)N_EDGES * HID) - ws);
    const bool fast = (ws_size >= need);
    (void)in_sizes; (void)n_in; (void)out_size;

    // fast-path overlays (regions dead during CSR build):
    int2* partK   = (int2*)h;              // E int2 = 12.8MB (h + y)
    int* histG    = (int*)aggr;            // NPBLK*NBIN = 256KB
    int* boffsG   = histG + NPBLK * NBIN;  // 256KB (aggr = 6.4MB: fits)
    int* binTot   = csr;                   // NBIN
    int* binStart = csr + NBIN;            // NBIN+1

    const int* srcA = eidx;
    const int* dstA = eidx + N_EDGES;

    if (fast) {
        // ---- key-only binned CSR build; edge-MLP at CSR position ----
        k_hist1<<<NPBLK, 256, 0, stream>>>(dstA, histG);
        k_scanblk<<<NBIN, NPBLK, 0, stream>>>(histG, boffsG, binTot);
        k_scanbin<<<1, NBIN, 0, stream>>>(binTot, binStart);
        k_partl<<<NPBLK, 256, 0, stream>>>(dstA, srcA, boffsG, binStart, partK);
        k_finishl<<<NBIN, 512, 0, stream>>>(partK, binStart, rowptr, srcP, csrE);
        k_permea<<<N_EDGES / 256, 256, 0, stream>>>(csrE, eattr, edge_w,
            edge_b, eaPh);
        // ---- layers ----
        k_embed<<<N_NODES / 16, 256, 0, stream>>>(x, node_w, node_b, y);
        const int gridA = (16 * N_NODES + 255) / 256;
        const int gridN = (N_NODES + 255) / 256;
        for (int l = 0; l < NL; ++l) {
            const int nidx = (l < 3) ? (l + 1) : 0;
            k_aggr<<<gridA, 256, 0, stream>>>(y, rowptr, srcP, eaPh, tArr, l, aggr);
            k_node<<<gridN, 256, 0, stream>>>(y, h, aggr,
                mlp_w1 + l * 512, mlp_b1 + l * 32, mlp_g1 + l * 32, mlp_be1 + l * 32,
                mlp_w2 + l * 512, mlp_b2 + l * 16, ln_g + nidx * 16, ln_b + nidx * 16,
                h, y, l);
        }
        k_pool<<<NB, 256, 0, stream>>>(y, batch, gmax, gsum, gcnt);
    } else {
        // ---- v0 fallback (round-4 proven): atomic CSR + fused k_layer ----
        hipMemsetAsync(cnt, 0, (size_t)N_NODES * sizeof(int), stream);
        k_count<<<(N_EDGES + 255) / 256, 256, 0, stream>>>(dstA, cnt);
        k_scan1<<<NSCAN_BLK, 256, 0, stream>>>(cnt, rowptr, bsum);
        k_scan2<<<1, 512, 0, stream>>>(bsum, offs, rowptr);
        k_scan3<<<NSCAN_BLK, 256, 0, stream>>>(rowptr, offs, cnt);
        k_fill<<<(N_EDGES + 255) / 256, 256, 0, stream>>>(dstA, rowptr, cnt, csr);
        float* yA = y;
        float* yB = aggr;
        k_embed<<<N_NODES / 16, 256, 0, stream>>>(x, node_w, node_b, yA);
        const int grid = (4 * N_NODES + 255) / 256;
        for (int l = 0; l < NL; ++l) {
            const float* yin = (l & 1) ? yB : yA;
            float* yout      = (l & 1) ? yA : yB;
            const int nidx = (l < 3) ? (l + 1) : 0;
            k_layer<<<grid, 256, 0, stream>>>(
                yin, h, rowptr, csr, srcA, eattr, edge_w, edge_b, tArr, l,
                mlp_w1 + l * 512, mlp_b1 + l * 32, mlp_g1 + l * 32, mlp_be1 + l * 32,
                mlp_w2 + l * 512, mlp_b2 + l * 16, ln_g + nidx * 16, ln_b + nidx * 16,
                h, yout);
        }
        k_pool<<<NB, 256, 0, stream>>>(yA, batch, gmax, gsum, gcnt);
    }
    k_final<<<NB, 128, 0, stream>>>(gmax, gsum, gcnt, action,
        pin_w, pin_b, ph_w, ph_b, po_w, po_b, out);
}